// Round 6
// baseline (918.666 us; speedup 1.0000x reference)
//
#include <hip/hip_runtime.h>
#include <cstdint>
#include <cstddef>

#define NFEAT 256
#define NCLS  16

typedef unsigned int uint;
typedef unsigned short ushort;
typedef __attribute__((ext_vector_type(8))) short short8;
typedef __attribute__((ext_vector_type(4))) float f32x4;

__device__ inline float blo(uint u) { return __uint_as_float(u << 16); }
__device__ inline float bhi(uint u) { return __uint_as_float(u & 0xffff0000u); }
__device__ inline ushort f2bf(float f) {
    uint b = __float_as_uint(f);
    b += 0x7fffu + ((b >> 16) & 1u);
    return (ushort)(b >> 16);
}
__device__ inline uint pack2(float a, float b) {
    return (uint)f2bf(a) | ((uint)f2bf(b) << 16);
}

// ---------------------------------------------------------------------------
// Graph build: bucketed counting sort (bucket = dst >> 8, 391 buckets)
// ---------------------------------------------------------------------------
__global__ __launch_bounds__(256) void k_ccount(const int* __restrict__ dst,
                                                int* __restrict__ bhist, int E, int nb) {
    __shared__ int h[512];
    int t = threadIdx.x;
    for (int i = t; i < nb; i += 256) h[i] = 0;
    __syncthreads();
    for (int i = blockIdx.x * 256 + t; i < E; i += gridDim.x * 256)
        atomicAdd(&h[dst[i] >> 8], 1);
    __syncthreads();
    for (int i = t; i < nb; i += 256)
        if (h[i]) atomicAdd(&bhist[i], h[i]);
}

__global__ __launch_bounds__(256) void k_cscan(const int* __restrict__ bhist,
                                               int* __restrict__ boff,
                                               int* __restrict__ gcur,
                                               int* __restrict__ rowptr,
                                               int nb, int Nn) {
    int t = threadIdx.x;
    int v0 = (2 * t < nb) ? bhist[2 * t] : 0;
    int v1 = (2 * t + 1 < nb) ? bhist[2 * t + 1] : 0;
    int s = v0 + v1;
    __shared__ int ps[256];
    ps[t] = s;
    __syncthreads();
    for (int off = 1; off < 256; off <<= 1) {
        int v = (t >= off) ? ps[t - off] : 0;
        __syncthreads();
        ps[t] += v;
        __syncthreads();
    }
    int ex = ps[t] - s;
    if (2 * t < nb)     { boff[2 * t] = ex;          gcur[2 * t] = ex; }
    if (2 * t + 1 < nb) { boff[2 * t + 1] = ex + v0; gcur[2 * t + 1] = ex + v0; }
    if (t == 255) { boff[nb] = ps[255]; rowptr[Nn] = ps[255]; }
}

__global__ __launch_bounds__(256) void k_cfill(const int* __restrict__ src,
                                               const int* __restrict__ dst,
                                               int* __restrict__ gcur,
                                               uint2* __restrict__ ebuf, int E, int nb) {
    __shared__ int hist[400];
    __shared__ int lstart[400];
    __shared__ int gbase[400];
    __shared__ int cur[400];
    __shared__ int ps[256];
    __shared__ uint2 stg[4096];
    __shared__ ushort sb[4096];
    int t = threadIdx.x;
    int base = blockIdx.x * 4096;
    int lim = min(4096, E - base);
    for (int i = t; i < nb; i += 256) hist[i] = 0;
    __syncthreads();
    for (int k = t; k < lim; k += 256) atomicAdd(&hist[dst[base + k] >> 8], 1);
    __syncthreads();
    int v0 = (2 * t < nb) ? hist[2 * t] : 0;
    int v1 = (2 * t + 1 < nb) ? hist[2 * t + 1] : 0;
    int s = v0 + v1;
    ps[t] = s;
    __syncthreads();
    for (int off = 1; off < 256; off <<= 1) {
        int v = (t >= off) ? ps[t - off] : 0;
        __syncthreads();
        ps[t] += v;
        __syncthreads();
    }
    int ex = ps[t] - s;
    if (2 * t < nb) {
        lstart[2 * t] = ex; cur[2 * t] = ex;
        if (v0) gbase[2 * t] = atomicAdd(&gcur[2 * t], v0);
    }
    if (2 * t + 1 < nb) {
        lstart[2 * t + 1] = ex + v0; cur[2 * t + 1] = ex + v0;
        if (v1) gbase[2 * t + 1] = atomicAdd(&gcur[2 * t + 1], v1);
    }
    __syncthreads();
    for (int k = t; k < lim; k += 256) {
        int s_ = src[base + k], d_ = dst[base + k];
        int b = d_ >> 8;
        int slot = atomicAdd(&cur[b], 1);
        stg[slot] = make_uint2((uint)s_, (uint)d_);
        sb[slot] = (ushort)b;
    }
    __syncthreads();
    for (int j = t; j < lim; j += 256) {
        int b = sb[j];
        ebuf[gbase[b] + (j - lstart[b])] = stg[j];
    }
}

__global__ __launch_bounds__(256) void k_rowbuild(const uint2* __restrict__ ebuf,
                                                  const int* __restrict__ boff,
                                                  int* __restrict__ rowptr,
                                                  float* __restrict__ dis,
                                                  int* __restrict__ csr_col,
                                                  int Nn, int nb) {
    int b = blockIdx.x;
    int t = threadIdx.x;
    int beg = boff[b], end = boff[b + 1];
    __shared__ int rcnt[256];
    __shared__ int rstart[256];
    __shared__ int ps[256];
    rcnt[t] = 0;
    __syncthreads();
    for (int e = beg + t; e < end; e += 256)
        atomicAdd(&rcnt[ebuf[e].y & 255], 1);
    __syncthreads();
    int v = rcnt[t];
    ps[t] = v;
    __syncthreads();
    for (int off = 1; off < 256; off <<= 1) {
        int u = (t >= off) ? ps[t - off] : 0;
        __syncthreads();
        ps[t] += u;
        __syncthreads();
    }
    int ex = ps[t] - v;
    int node = b * 256 + t;
    if (node < Nn) {
        rowptr[node] = beg + ex;
        dis[node] = rsqrtf((float)(v + 1));
    }
    rstart[t] = beg + ex;
    __syncthreads();
    rcnt[t] = 0;
    __syncthreads();
    for (int e = beg + t; e < end; e += 256) {
        uint2 ed = ebuf[e];
        int r = ed.y & 255;
        int slot = atomicAdd(&rcnt[r], 1);
        csr_col[rstart[r] + slot] = (int)ed.x;
    }
}

__global__ void k_val(const int* __restrict__ col, const float* __restrict__ dis,
                      float* __restrict__ val, int E) {
    int i = blockIdx.x * 256 + threadIdx.x;
    if (i < E) val[i] = dis[col[i]];
}

// ---------------------------------------------------------------------------
// small dense helpers
// ---------------------------------------------------------------------------
__global__ __launch_bounds__(256) void k_mm256(const float* __restrict__ A,
                                               const float* __restrict__ B,
                                               float* __restrict__ C) {
    int i = blockIdx.x, j = threadIdx.x;
    float acc = 0.f;
    for (int k = 0; k < 256; ++k) acc = fmaf(A[i * 256 + k], B[k * 256 + j], acc);
    C[i * 256 + j] = acc;
}

__global__ __launch_bounds__(256) void k_vm256(const float* __restrict__ v,
                                               const float* __restrict__ M,
                                               float* __restrict__ r) {
    int j = threadIdx.x;
    float acc = 0.f;
    for (int k = 0; k < 256; ++k) acc = fmaf(v[k], M[(size_t)k * 256 + j], acc);
    r[j] = acc;
}

// pack Wc (fp32 [256][256]) into MFMA B-fragment layout, bf16.
__global__ __launch_bounds__(256) void k_pack(const float* __restrict__ W,
                                              uint* __restrict__ Wp) {
    int idx = blockIdx.x * 256 + threadIdx.x;   // 32768 words
    int w = idx & 3, lane = (idx >> 2) & 63, kstep = (idx >> 8) & 7, n16 = idx >> 11;
    int n = n16 * 16 + (lane & 15);
    int k = kstep * 32 + (lane >> 4) * 8 + 2 * w;
    Wp[idx] = pack2(W[k * 256 + n], W[(k + 1) * 256 + n]);
}

// ---------------------------------------------------------------------------
// MFMA GEMM: C[M,256](bf16) = A[M,256](fp32) @ Wp(bf16 frags)
// block = 4 waves; wave computes 16 rows x ALL 256 cols (A read exactly once)
// ---------------------------------------------------------------------------
__global__ __launch_bounds__(256) void gemm_mfma(const float* __restrict__ A,
                                                 const uint* __restrict__ Wp,
                                                 ushort* __restrict__ C, int M) {
    int t = threadIdx.x;
    int wv = t >> 6;
    int l = t & 63;
    int m16 = l & 15;
    int kc = l >> 4;
    int bm = blockIdx.x * 64 + wv * 16;
    int row = bm + m16;
    bool valid = row < M;
    const float* ap = A + (size_t)(valid ? row : 0) * 256 + kc * 8;
    const short8* wp = (const short8*)Wp;

    f32x4 acc[16];
#pragma unroll
    for (int n = 0; n < 16; ++n) acc[n] = {0.f, 0.f, 0.f, 0.f};

    for (int ks = 0; ks < 8; ++ks) {
        float4 fa0 = make_float4(0.f, 0.f, 0.f, 0.f), fa1 = fa0;
        if (valid) {
            fa0 = *(const float4*)(ap + ks * 32);
            fa1 = *(const float4*)(ap + ks * 32 + 4);
        }
        short8 a;
        a[0] = (short)f2bf(fa0.x); a[1] = (short)f2bf(fa0.y);
        a[2] = (short)f2bf(fa0.z); a[3] = (short)f2bf(fa0.w);
        a[4] = (short)f2bf(fa1.x); a[5] = (short)f2bf(fa1.y);
        a[6] = (short)f2bf(fa1.z); a[7] = (short)f2bf(fa1.w);
#pragma unroll
        for (int n = 0; n < 16; ++n) {
            short8 b = wp[(n * 8 + ks) * 64 + l];
            acc[n] = __builtin_amdgcn_mfma_f32_16x16x32_bf16(a, b, acc[n], 0, 0, 0);
        }
    }

    // C/D layout: col = lane&15, row = (lane>>4)*4 + reg   [m89-verified]
#pragma unroll
    for (int r = 0; r < 4; ++r) {
        int orow = bm + kc * 4 + r;
        if (orow < M) {
            ushort* cp = C + (size_t)orow * 256 + m16;
#pragma unroll
            for (int n = 0; n < 16; ++n) cp[n * 16] = f2bf(acc[n][r]);
        }
    }
}

// scalar propagation: sout = A_hat * sin   (FIRST: sin == ones)
template <int FIRST>
__global__ __launch_bounds__(256) void k_svec(const float* __restrict__ sin,
                                              const int* __restrict__ rowptr,
                                              const int* __restrict__ col,
                                              const float* __restrict__ val,
                                              const float* __restrict__ dis,
                                              float* __restrict__ sout, int Nn) {
    int d = blockIdx.x * 256 + threadIdx.x;
    if (d >= Nn) return;
    int beg = rowptr[d], end = rowptr[d + 1];
    float acc = 0.f;
    if (FIRST) {
        for (int e = beg; e < end; ++e) acc += val[e];
    } else {
        for (int e = beg; e < end; ++e) acc = fmaf(val[e], sin[col[e]], acc);
    }
    float dd = dis[d];
    sout[d] = fmaf(dd, acc, dd * dd * (FIRST ? 1.f : sin[d]));
}

// ---------------------------------------------------------------------------
// bf16 propagation: out[d] = bf16( dis_d*sum(val*y[col]) + dis_d^2*y[d] [+rank1] )
// 256-thread blocks = 4 waves = 4 nodes; lane owns 4 features (uint2 = 8B);
// 8 edges in flight per wave.
// ---------------------------------------------------------------------------
template <int FINAL>
__global__ __launch_bounds__(256) void k_aggb(const uint* __restrict__ y,
                                              const int* __restrict__ rowptr,
                                              const int* __restrict__ col,
                                              const float* __restrict__ val,
                                              const float* __restrict__ dis,
                                              const float* __restrict__ s1,
                                              const float* __restrict__ s2,
                                              const float* __restrict__ s3,
                                              const float* __restrict__ c1,
                                              const float* __restrict__ c2,
                                              const float* __restrict__ c3,
                                              const float* __restrict__ c4,
                                              uint* __restrict__ out, int Nn) {
    int wid = threadIdx.x >> 6;
    int t = threadIdx.x & 63;
    int d = blockIdx.x * 4 + wid;
    if (d >= Nn) return;
    const uint* yt = y + 2 * t;
    int beg = rowptr[d], end = rowptr[d + 1];
    float a0 = 0.f, a1 = 0.f, a2 = 0.f, a3 = 0.f;
    int e = beg;
    for (; e + 7 < end; e += 8) {
        int cc[8]; float vv[8]; uint2 uu[8];
#pragma unroll
        for (int j = 0; j < 8; ++j) { cc[j] = col[e + j]; vv[j] = val[e + j]; }
#pragma unroll
        for (int j = 0; j < 8; ++j) uu[j] = *(const uint2*)(yt + (size_t)cc[j] * 128);
#pragma unroll
        for (int j = 0; j < 8; ++j) {
            a0 = fmaf(vv[j], blo(uu[j].x), a0);
            a1 = fmaf(vv[j], bhi(uu[j].x), a1);
            a2 = fmaf(vv[j], blo(uu[j].y), a2);
            a3 = fmaf(vv[j], bhi(uu[j].y), a3);
        }
    }
    if (e + 3 < end) {
        int cc[4]; float vv[4]; uint2 uu[4];
#pragma unroll
        for (int j = 0; j < 4; ++j) { cc[j] = col[e + j]; vv[j] = val[e + j]; }
#pragma unroll
        for (int j = 0; j < 4; ++j) uu[j] = *(const uint2*)(yt + (size_t)cc[j] * 128);
#pragma unroll
        for (int j = 0; j < 4; ++j) {
            a0 = fmaf(vv[j], blo(uu[j].x), a0);
            a1 = fmaf(vv[j], bhi(uu[j].x), a1);
            a2 = fmaf(vv[j], blo(uu[j].y), a2);
            a3 = fmaf(vv[j], bhi(uu[j].y), a3);
        }
        e += 4;
    }
    for (; e < end; ++e) {
        int c = col[e]; float v = val[e];
        uint2 u = *(const uint2*)(yt + (size_t)c * 128);
        a0 = fmaf(v, blo(u.x), a0); a1 = fmaf(v, bhi(u.x), a1);
        a2 = fmaf(v, blo(u.y), a2); a3 = fmaf(v, bhi(u.y), a3);
    }
    float dd = dis[d];
    float d2 = dd * dd;
    uint2 us = *(const uint2*)(yt + (size_t)d * 128);
    float r0 = fmaf(dd, a0, d2 * blo(us.x));
    float r1 = fmaf(dd, a1, d2 * bhi(us.x));
    float r2 = fmaf(dd, a2, d2 * blo(us.y));
    float r3 = fmaf(dd, a3, d2 * bhi(us.y));
    if (FINAL) {
        float4 C1 = *(const float4*)(c1 + 4 * t);
        float4 C2 = *(const float4*)(c2 + 4 * t);
        float4 C3 = *(const float4*)(c3 + 4 * t);
        float4 C4 = *(const float4*)(c4 + 4 * t);
        float S1 = s1[d], S2 = s2[d], S3 = s3[d];
        r0 += S3 * C1.x + S2 * C2.x + S1 * C3.x + C4.x;
        r1 += S3 * C1.y + S2 * C2.y + S1 * C3.y + C4.y;
        r2 += S3 * C1.z + S2 * C2.z + S1 * C3.z + C4.z;
        r3 += S3 * C1.w + S2 * C2.w + S1 * C3.w + C4.w;
    }
    uint2 o;
    o.x = pack2(r0, r1);
    o.y = pack2(r2, r3);
    *(uint2*)(out + (size_t)d * 128 + 2 * t) = o;
}

// ---------------------------------------------------------------------------
// final layer: Y[M,16](f32) = relu(A[M,256](bf16)) @ W2[256,16](f32)
// ---------------------------------------------------------------------------
__global__ __launch_bounds__(256) void k_gemm16b(const uint* __restrict__ A,
                                                 const float* __restrict__ W2,
                                                 float* __restrict__ Y, int M) {
    __shared__ float Ws[256][16];
    int t = threadIdx.x;
    for (int i = t; i < 256 * 16; i += 256) Ws[i >> 4][i & 15] = W2[i];
    __syncthreads();
    int tx = t & 15, ty = t >> 4;
    int r = blockIdx.x * 16 + ty;
    if (r >= M) return;
    const uint* a = A + (size_t)r * 128;
    float acc = 0.f;
    for (int i = 0; i < 128; i += 4) {
        uint4 u = *(const uint4*)(a + i);
        float f;
        f = fmaxf(blo(u.x), 0.f); acc = fmaf(f, Ws[2 * i + 0][tx], acc);
        f = fmaxf(bhi(u.x), 0.f); acc = fmaf(f, Ws[2 * i + 1][tx], acc);
        f = fmaxf(blo(u.y), 0.f); acc = fmaf(f, Ws[2 * i + 2][tx], acc);
        f = fmaxf(bhi(u.y), 0.f); acc = fmaf(f, Ws[2 * i + 3][tx], acc);
        f = fmaxf(blo(u.z), 0.f); acc = fmaf(f, Ws[2 * i + 4][tx], acc);
        f = fmaxf(bhi(u.z), 0.f); acc = fmaf(f, Ws[2 * i + 5][tx], acc);
        f = fmaxf(blo(u.w), 0.f); acc = fmaf(f, Ws[2 * i + 6][tx], acc);
        f = fmaxf(bhi(u.w), 0.f); acc = fmaf(f, Ws[2 * i + 7][tx], acc);
    }
    Y[(size_t)r * NCLS + tx] = acc;
}

// propagation at width 16 (fp32)
__global__ __launch_bounds__(256) void k_agg16(const float* __restrict__ y16,
                                               const int* __restrict__ rowptr,
                                               const int* __restrict__ col,
                                               const float* __restrict__ val,
                                               const float* __restrict__ dis,
                                               const float* __restrict__ b2,
                                               float* __restrict__ out, int Nn) {
    int t = threadIdx.x;
    int tx = t & 15, ty = t >> 4;
    int d = blockIdx.x * 16 + ty;
    if (d >= Nn) return;
    int beg = rowptr[d], end = rowptr[d + 1];
    float acc = 0.f;
    for (int e = beg; e < end; ++e)
        acc = fmaf(val[e], y16[(size_t)col[e] * NCLS + tx], acc);
    float dd = dis[d];
    out[(size_t)d * NCLS + tx] = dd * acc + dd * dd * y16[(size_t)d * NCLS + tx] + b2[tx];
}

// ---------------------------------------------------------------------------
// softmax over axis 0
// ---------------------------------------------------------------------------
__global__ __launch_bounds__(256) void k_sm1(const float* __restrict__ z,
                                             float* __restrict__ pmax,
                                             float* __restrict__ psum, int Nn) {
    int b = blockIdx.x, t = threadIdx.x, tx = t & 15, ty = t >> 4;
    int CH = (Nn + 255) / 256;
    int r0 = b * CH, r1 = min(r0 + CH, Nn);
    __shared__ float red[16][17];
    __shared__ float gloc[16];
    float m = -3.4e38f;
    for (int r = r0 + ty; r < r1; r += 16) m = fmaxf(m, z[(size_t)r * NCLS + tx]);
    red[ty][tx] = m;
    __syncthreads();
    if (ty == 0) {
        float mm = red[0][tx];
#pragma unroll
        for (int i = 1; i < 16; ++i) mm = fmaxf(mm, red[i][tx]);
        gloc[tx] = mm;
    }
    __syncthreads();
    float g = gloc[tx];
    float s = 0.f;
    for (int r = r0 + ty; r < r1; r += 16) s += expf(z[(size_t)r * NCLS + tx] - g);
    red[ty][tx] = s;
    __syncthreads();
    if (ty == 0) {
        float ss = red[0][tx];
#pragma unroll
        for (int i = 1; i < 16; ++i) ss += red[i][tx];
        pmax[b * 16 + tx] = g;
        psum[b * 16 + tx] = ss;
    }
}

__global__ __launch_bounds__(256) void k_sm2(const float* __restrict__ pmax,
                                             const float* __restrict__ psum,
                                             float* __restrict__ g16,
                                             float* __restrict__ inv16) {
    int t = threadIdx.x, tx = t & 15, ty = t >> 4;
    __shared__ float red[16][17];
    __shared__ float gsh[16];
    float m = -3.4e38f;
    for (int b = ty; b < 256; b += 16) m = fmaxf(m, pmax[b * 16 + tx]);
    red[ty][tx] = m;
    __syncthreads();
    if (ty == 0) {
        float mm = red[0][tx];
#pragma unroll
        for (int i = 1; i < 16; ++i) mm = fmaxf(mm, red[i][tx]);
        gsh[tx] = mm;
    }
    __syncthreads();
    float g = gsh[tx];
    float s = 0.f;
    for (int b = ty; b < 256; b += 16)
        s += psum[b * 16 + tx] * expf(pmax[b * 16 + tx] - g);
    red[ty][tx] = s;
    __syncthreads();
    if (ty == 0) {
        float ss = red[0][tx];
#pragma unroll
        for (int i = 1; i < 16; ++i) ss += red[i][tx];
        g16[tx] = g;
        inv16[tx] = 1.0f / ss;
    }
}

__global__ void k_sm5(float* __restrict__ z, const float* __restrict__ g16,
                      const float* __restrict__ inv16, int total) {
    int i = blockIdx.x * 256 + threadIdx.x;
    if (i < total) {
        int c = i & 15;
        z[i] = expf(z[i] - g16[c]) * inv16[c];
    }
}

// ---------------------------------------------------------------------------
extern "C" void kernel_launch(void* const* d_in, const int* in_sizes, int n_in,
                              void* d_out, int out_size, void* d_ws, size_t ws_size,
                              hipStream_t stream) {
    const float* x  = (const float*)d_in[0];
    const int*   ei = (const int*)d_in[1];
    const float* W1 = (const float*)d_in[2];
    const float* b1 = (const float*)d_in[3];
    const float* Wi = (const float*)d_in[4];
    const float* bi = (const float*)d_in[5];
    const float* W2 = (const float*)d_in[6];
    const float* b2 = (const float*)d_in[7];
    float* out = (float*)d_out;

    int Nn = in_sizes[0] / NFEAT;   // 100000
    int E  = in_sizes[1] / 2;       // 1600000
    int nb = (Nn + 255) >> 8;       // 391 coarse buckets
    const int* esrc = ei;
    const int* edst = ei + E;

    char* p = (char*)d_ws;
    auto carve = [&](size_t bytes) -> char* {
        char* r = p;
        p += (bytes + 255) / 256 * 256;
        return r;
    };
    uint*  bufA    = (uint*) carve((size_t)Nn * 128 * 4);   // bf16 features
    uint*  bufB    = (uint*) carve((size_t)Nn * 128 * 4);
    int*   rowptr  = (int*)  carve((size_t)(Nn + 1) * 4);
    float* dis     = (float*)carve((size_t)Nn * 4);
    int*   csr_col = (int*)  carve((size_t)E * 4);
    float* csr_val = (float*)carve((size_t)E * 4);
    uint2* ebuf    = (uint2*)carve((size_t)E * 8);
    int*   bhist   = (int*)  carve(512 * 4);
    int*   boff    = (int*)  carve(512 * 4);
    int*   gcur    = (int*)  carve(512 * 4);
    float* y16     = (float*)carve((size_t)Nn * NCLS * 4);
    float* s1      = (float*)carve((size_t)Nn * 4);
    float* s2      = (float*)carve((size_t)Nn * 4);
    float* s3      = (float*)carve((size_t)Nn * 4);
    float* WA      = (float*)carve(256 * 256 * 4);
    float* WB      = (float*)carve(256 * 256 * 4);
    float* Wc      = (float*)carve(256 * 256 * 4);
    uint*  Wp      = (uint*) carve(32768 * 4);
    float* c1      = (float*)carve(256 * 4);
    float* c2      = (float*)carve(256 * 4);
    float* c3      = (float*)carve(256 * 4);
    float* u1      = (float*)carve(256 * 4);
    float* u2      = (float*)carve(256 * 4);
    float* pmax    = (float*)carve(256 * 16 * 4);
    float* psum    = (float*)carve(256 * 16 * 4);
    float* g16     = (float*)carve(16 * 4);
    float* inv16   = (float*)carve(16 * 4);

    hipMemsetAsync(bhist, 0, 512 * 4, stream);

    int gE = (E + 255) / 256;
    int gN = (Nn + 255) / 256;
    int nch = (E + 4095) / 4096;

    // graph build (bucketed counting sort)
    k_ccount<<<1024, 256, 0, stream>>>(edst, bhist, E, nb);
    k_cscan<<<1, 256, 0, stream>>>(bhist, boff, gcur, rowptr, nb, Nn);
    k_cfill<<<nch, 256, 0, stream>>>(esrc, edst, gcur, ebuf, E, nb);
    k_rowbuild<<<nb, 256, 0, stream>>>(ebuf, boff, rowptr, dis, csr_col, Nn, nb);
    k_val<<<gE, 256, 0, stream>>>(csr_col, dis, csr_val, E);

    // weight chain: Wc = W1 Wi^3 ; c1 = b1 Wi^3, c2 = bi Wi^2, c3 = bi Wi, c4 = bi
    k_mm256<<<256, 256, 0, stream>>>(W1, Wi, WA);
    k_mm256<<<256, 256, 0, stream>>>(WA, Wi, WB);
    k_mm256<<<256, 256, 0, stream>>>(WB, Wi, Wc);
    k_pack<<<128, 256, 0, stream>>>(Wc, Wp);
    k_vm256<<<1, 256, 0, stream>>>(bi, Wi, c3);
    k_vm256<<<1, 256, 0, stream>>>(c3, Wi, c2);
    k_vm256<<<1, 256, 0, stream>>>(b1, Wi, u1);
    k_vm256<<<1, 256, 0, stream>>>(u1, Wi, u2);
    k_vm256<<<1, 256, 0, stream>>>(u2, Wi, c1);

    // scalar propagation vectors s1 = A1, s2 = A^2 1, s3 = A^3 1
    k_svec<1><<<gN, 256, 0, stream>>>(nullptr, rowptr, csr_col, csr_val, dis, s1, Nn);
    k_svec<0><<<gN, 256, 0, stream>>>(s1, rowptr, csr_col, csr_val, dis, s2, Nn);
    k_svec<0><<<gN, 256, 0, stream>>>(s2, rowptr, csr_col, csr_val, dis, s3, Nn);

    // y0 = x @ Wc  (bf16 out, MFMA; A read once)
    gemm_mfma<<<(Nn + 63) / 64, 256, 0, stream>>>(x, Wp, (ushort*)bufB, Nn);

    // h4 = A^4 y0 + rank-1 terms (in the last pass)
    int gA = (Nn + 3) / 4;
    k_aggb<0><<<gA, 256, 0, stream>>>(bufB, rowptr, csr_col, csr_val, dis,
                                      nullptr, nullptr, nullptr, nullptr, nullptr, nullptr, nullptr, bufA, Nn);
    k_aggb<0><<<gA, 256, 0, stream>>>(bufA, rowptr, csr_col, csr_val, dis,
                                      nullptr, nullptr, nullptr, nullptr, nullptr, nullptr, nullptr, bufB, Nn);
    k_aggb<0><<<gA, 256, 0, stream>>>(bufB, rowptr, csr_col, csr_val, dis,
                                      nullptr, nullptr, nullptr, nullptr, nullptr, nullptr, nullptr, bufA, Nn);
    k_aggb<1><<<gA, 256, 0, stream>>>(bufA, rowptr, csr_col, csr_val, dis,
                                      s1, s2, s3, c1, c2, c3, bi, bufB, Nn);

    // final: z = A(relu(h4) W2) + b2 ; softmax over nodes
    int g16b = (Nn + 15) / 16;
    k_gemm16b<<<g16b, 256, 0, stream>>>(bufB, W2, y16, Nn);
    k_agg16<<<g16b, 256, 0, stream>>>(y16, rowptr, csr_col, csr_val, dis, b2, out, Nn);

    k_sm1<<<256, 256, 0, stream>>>(out, pmax, psum, Nn);
    k_sm2<<<1, 256, 0, stream>>>(pmax, psum, g16, inv16);
    k_sm5<<<(Nn * NCLS + 255) / 256, 256, 0, stream>>>(out, g16, inv16, Nn * NCLS);
}

// Round 7
// 903.192 us; speedup vs baseline: 1.0171x; 1.0171x over previous
//
#include <hip/hip_runtime.h>
#include <cstdint>
#include <cstddef>

#define NFEAT 256
#define NCLS  16

typedef unsigned int uint;
typedef unsigned short ushort;
typedef __attribute__((ext_vector_type(8))) short short8;
typedef __attribute__((ext_vector_type(4))) float f32x4;

__device__ inline float blo(uint u) { return __uint_as_float(u << 16); }
__device__ inline float bhi(uint u) { return __uint_as_float(u & 0xffff0000u); }
__device__ inline ushort f2bf(float f) {
    uint b = __float_as_uint(f);
    b += 0x7fffu + ((b >> 16) & 1u);
    return (ushort)(b >> 16);
}
__device__ inline uint pack2(float a, float b) {
    return (uint)f2bf(a) | ((uint)f2bf(b) << 16);
}

// ---------------------------------------------------------------------------
// Graph build: bucketed counting sort (bucket = dst >> 8, 391 buckets)
// ---------------------------------------------------------------------------
__global__ __launch_bounds__(256) void k_ccount(const int* __restrict__ dst,
                                                int* __restrict__ bhist, int E, int nb) {
    __shared__ int h[512];
    int t = threadIdx.x;
    for (int i = t; i < nb; i += 256) h[i] = 0;
    __syncthreads();
    for (int i = blockIdx.x * 256 + t; i < E; i += gridDim.x * 256)
        atomicAdd(&h[dst[i] >> 8], 1);
    __syncthreads();
    for (int i = t; i < nb; i += 256)
        if (h[i]) atomicAdd(&bhist[i], h[i]);
}

__global__ __launch_bounds__(256) void k_cscan(const int* __restrict__ bhist,
                                               int* __restrict__ boff,
                                               int* __restrict__ gcur,
                                               int* __restrict__ rowptr,
                                               int nb, int Nn) {
    int t = threadIdx.x;
    int v0 = (2 * t < nb) ? bhist[2 * t] : 0;
    int v1 = (2 * t + 1 < nb) ? bhist[2 * t + 1] : 0;
    int s = v0 + v1;
    __shared__ int ps[256];
    ps[t] = s;
    __syncthreads();
    for (int off = 1; off < 256; off <<= 1) {
        int v = (t >= off) ? ps[t - off] : 0;
        __syncthreads();
        ps[t] += v;
        __syncthreads();
    }
    int ex = ps[t] - s;
    if (2 * t < nb)     { boff[2 * t] = ex;          gcur[2 * t] = ex; }
    if (2 * t + 1 < nb) { boff[2 * t + 1] = ex + v0; gcur[2 * t + 1] = ex + v0; }
    if (t == 255) { boff[nb] = ps[255]; rowptr[Nn] = ps[255]; }
}

__global__ __launch_bounds__(256) void k_cfill(const int* __restrict__ src,
                                               const int* __restrict__ dst,
                                               int* __restrict__ gcur,
                                               uint2* __restrict__ ebuf, int E, int nb) {
    __shared__ int hist[400];
    __shared__ int lstart[400];
    __shared__ int gbase[400];
    __shared__ int cur[400];
    __shared__ int ps[256];
    __shared__ uint2 stg[4096];
    __shared__ ushort sb[4096];
    int t = threadIdx.x;
    int base = blockIdx.x * 4096;
    int lim = min(4096, E - base);
    for (int i = t; i < nb; i += 256) hist[i] = 0;
    __syncthreads();
    for (int k = t; k < lim; k += 256) atomicAdd(&hist[dst[base + k] >> 8], 1);
    __syncthreads();
    int v0 = (2 * t < nb) ? hist[2 * t] : 0;
    int v1 = (2 * t + 1 < nb) ? hist[2 * t + 1] : 0;
    int s = v0 + v1;
    ps[t] = s;
    __syncthreads();
    for (int off = 1; off < 256; off <<= 1) {
        int v = (t >= off) ? ps[t - off] : 0;
        __syncthreads();
        ps[t] += v;
        __syncthreads();
    }
    int ex = ps[t] - s;
    if (2 * t < nb) {
        lstart[2 * t] = ex; cur[2 * t] = ex;
        if (v0) gbase[2 * t] = atomicAdd(&gcur[2 * t], v0);
    }
    if (2 * t + 1 < nb) {
        lstart[2 * t + 1] = ex + v0; cur[2 * t + 1] = ex + v0;
        if (v1) gbase[2 * t + 1] = atomicAdd(&gcur[2 * t + 1], v1);
    }
    __syncthreads();
    for (int k = t; k < lim; k += 256) {
        int s_ = src[base + k], d_ = dst[base + k];
        int b = d_ >> 8;
        int slot = atomicAdd(&cur[b], 1);
        stg[slot] = make_uint2((uint)s_, (uint)d_);
        sb[slot] = (ushort)b;
    }
    __syncthreads();
    for (int j = t; j < lim; j += 256) {
        int b = sb[j];
        ebuf[gbase[b] + (j - lstart[b])] = stg[j];
    }
}

__global__ __launch_bounds__(256) void k_rowbuild(const uint2* __restrict__ ebuf,
                                                  const int* __restrict__ boff,
                                                  int* __restrict__ rowptr,
                                                  float* __restrict__ dis,
                                                  int* __restrict__ csr_col,
                                                  int Nn, int nb) {
    int b = blockIdx.x;
    int t = threadIdx.x;
    int beg = boff[b], end = boff[b + 1];
    __shared__ int rcnt[256];
    __shared__ int rstart[256];
    __shared__ int ps[256];
    rcnt[t] = 0;
    __syncthreads();
    for (int e = beg + t; e < end; e += 256)
        atomicAdd(&rcnt[ebuf[e].y & 255], 1);
    __syncthreads();
    int v = rcnt[t];
    ps[t] = v;
    __syncthreads();
    for (int off = 1; off < 256; off <<= 1) {
        int u = (t >= off) ? ps[t - off] : 0;
        __syncthreads();
        ps[t] += u;
        __syncthreads();
    }
    int ex = ps[t] - v;
    int node = b * 256 + t;
    if (node < Nn) {
        rowptr[node] = beg + ex;
        dis[node] = rsqrtf((float)(v + 1));
    }
    rstart[t] = beg + ex;
    __syncthreads();
    rcnt[t] = 0;
    __syncthreads();
    for (int e = beg + t; e < end; e += 256) {
        uint2 ed = ebuf[e];
        int r = ed.y & 255;
        int slot = atomicAdd(&rcnt[r], 1);
        csr_col[rstart[r] + slot] = (int)ed.x;
    }
}

__global__ void k_val(const int* __restrict__ col, const float* __restrict__ dis,
                      float* __restrict__ val, int E) {
    int i = blockIdx.x * 256 + threadIdx.x;
    if (i < E) val[i] = dis[col[i]];
}

// ---------------------------------------------------------------------------
// small dense helpers
// ---------------------------------------------------------------------------
__global__ __launch_bounds__(256) void k_mm256(const float* __restrict__ A,
                                               const float* __restrict__ B,
                                               float* __restrict__ C) {
    int i = blockIdx.x, j = threadIdx.x;
    float acc = 0.f;
    for (int k = 0; k < 256; ++k) acc = fmaf(A[i * 256 + k], B[k * 256 + j], acc);
    C[i * 256 + j] = acc;
}

__global__ __launch_bounds__(256) void k_vm256(const float* __restrict__ v,
                                               const float* __restrict__ M,
                                               float* __restrict__ r) {
    int j = threadIdx.x;
    float acc = 0.f;
    for (int k = 0; k < 256; ++k) acc = fmaf(v[k], M[(size_t)k * 256 + j], acc);
    r[j] = acc;
}

// pack Wc (fp32 [256][256]) into MFMA B-fragment layout, bf16.
__global__ __launch_bounds__(256) void k_pack(const float* __restrict__ W,
                                              uint* __restrict__ Wp) {
    int idx = blockIdx.x * 256 + threadIdx.x;   // 32768 words
    int w = idx & 3, lane = (idx >> 2) & 63, kstep = (idx >> 8) & 7, n16 = idx >> 11;
    int n = n16 * 16 + (lane & 15);
    int k = kstep * 32 + (lane >> 4) * 8 + 2 * w;
    Wp[idx] = pack2(W[k * 256 + n], W[(k + 1) * 256 + n]);
}

// x (fp32) -> xb (bf16), 8 elems/thread
__global__ __launch_bounds__(256) void k_tobf(const float* __restrict__ x,
                                              uint* __restrict__ xb, int total8) {
    int i = blockIdx.x * 256 + threadIdx.x;
    if (i >= total8) return;
    const float4* xp = (const float4*)x;
    float4 f0 = xp[2 * (size_t)i], f1 = xp[2 * (size_t)i + 1];
    uint4 o;
    o.x = pack2(f0.x, f0.y); o.y = pack2(f0.z, f0.w);
    o.z = pack2(f1.x, f1.y); o.w = pack2(f1.z, f1.w);
    ((uint4*)xb)[i] = o;
}

// ---------------------------------------------------------------------------
// MFMA GEMM: C[M,256](bf16) = xb[M,256](bf16) @ Wp(bf16 frags)
// grid (ceil(M/64), 2); block 4 waves; wave = 16 rows x 128 cols, acc[8]
// ---------------------------------------------------------------------------
__global__ __launch_bounds__(256) void gemm_mfma(const uint* __restrict__ Ab,
                                                 const uint* __restrict__ Wp,
                                                 ushort* __restrict__ C, int M) {
    int t = threadIdx.x;
    int wv = t >> 6;
    int l = t & 63;
    int m16 = l & 15;
    int kc = l >> 4;
    int bm = blockIdx.x * 64 + wv * 16;
    int n16b = blockIdx.y * 8;          // 8 n16-tiles = 128 cols
    int row = bm + m16;
    bool valid = row < M;
    const uint* ap = Ab + (size_t)(valid ? row : 0) * 128 + kc * 4;  // uint=2bf16
    const short8* wp = (const short8*)Wp;

    f32x4 acc[8];
#pragma unroll
    for (int n = 0; n < 8; ++n) acc[n] = {0.f, 0.f, 0.f, 0.f};

#pragma unroll
    for (int ks = 0; ks < 8; ++ks) {
        short8 a = *(const short8*)(ap + (size_t)ks * 16);   // 16B: k = ks*32+kc*8 ..+8
#pragma unroll
        for (int n = 0; n < 8; ++n) {
            short8 b = wp[((n16b + n) * 8 + ks) * 64 + l];
            acc[n] = __builtin_amdgcn_mfma_f32_16x16x32_bf16(a, b, acc[n], 0, 0, 0);
        }
    }

    // C/D layout: col = lane&15, row = (lane>>4)*4 + reg   [m89-verified]
#pragma unroll
    for (int r = 0; r < 4; ++r) {
        int orow = bm + kc * 4 + r;
        if (orow < M) {
            ushort* cp = C + (size_t)orow * 256 + n16b * 16 + m16;
#pragma unroll
            for (int n = 0; n < 8; ++n) cp[n * 16] = f2bf(acc[n][r]);
        }
    }
}

// scalar propagation: sout = A_hat * sin   (FIRST: sin == ones)
template <int FIRST>
__global__ __launch_bounds__(256) void k_svec(const float* __restrict__ sin,
                                              const int* __restrict__ rowptr,
                                              const int* __restrict__ col,
                                              const float* __restrict__ val,
                                              const float* __restrict__ dis,
                                              float* __restrict__ sout, int Nn) {
    int d = blockIdx.x * 256 + threadIdx.x;
    if (d >= Nn) return;
    int beg = rowptr[d], end = rowptr[d + 1];
    float acc = 0.f;
    if (FIRST) {
        for (int e = beg; e < end; ++e) acc += val[e];
    } else {
        for (int e = beg; e < end; ++e) acc = fmaf(val[e], sin[col[e]], acc);
    }
    float dd = dis[d];
    sout[d] = fmaf(dd, acc, dd * dd * (FIRST ? 1.f : sin[d]));
}

// ---------------------------------------------------------------------------
// bf16 propagation: out[d] = bf16( dis_d*sum(val*y[col]) + dis_d^2*y[d] [+rank1] )
// 256-thread blocks = 4 waves = 4 nodes; lane owns 4 features (uint2 = 8B);
// 8 edges in flight per wave.
// ---------------------------------------------------------------------------
template <int FINAL>
__global__ __launch_bounds__(256) void k_aggb(const uint* __restrict__ y,
                                              const int* __restrict__ rowptr,
                                              const int* __restrict__ col,
                                              const float* __restrict__ val,
                                              const float* __restrict__ dis,
                                              const float* __restrict__ s1,
                                              const float* __restrict__ s2,
                                              const float* __restrict__ s3,
                                              const float* __restrict__ c1,
                                              const float* __restrict__ c2,
                                              const float* __restrict__ c3,
                                              const float* __restrict__ c4,
                                              uint* __restrict__ out, int Nn) {
    int wid = threadIdx.x >> 6;
    int t = threadIdx.x & 63;
    int d = blockIdx.x * 4 + wid;
    if (d >= Nn) return;
    const uint* yt = y + 2 * t;
    int beg = rowptr[d], end = rowptr[d + 1];
    float a0 = 0.f, a1 = 0.f, a2 = 0.f, a3 = 0.f;
    int e = beg;
    for (; e + 7 < end; e += 8) {
        int cc[8]; float vv[8]; uint2 uu[8];
#pragma unroll
        for (int j = 0; j < 8; ++j) { cc[j] = col[e + j]; vv[j] = val[e + j]; }
#pragma unroll
        for (int j = 0; j < 8; ++j) uu[j] = *(const uint2*)(yt + (size_t)cc[j] * 128);
#pragma unroll
        for (int j = 0; j < 8; ++j) {
            a0 = fmaf(vv[j], blo(uu[j].x), a0);
            a1 = fmaf(vv[j], bhi(uu[j].x), a1);
            a2 = fmaf(vv[j], blo(uu[j].y), a2);
            a3 = fmaf(vv[j], bhi(uu[j].y), a3);
        }
    }
    if (e + 3 < end) {
        int cc[4]; float vv[4]; uint2 uu[4];
#pragma unroll
        for (int j = 0; j < 4; ++j) { cc[j] = col[e + j]; vv[j] = val[e + j]; }
#pragma unroll
        for (int j = 0; j < 4; ++j) uu[j] = *(const uint2*)(yt + (size_t)cc[j] * 128);
#pragma unroll
        for (int j = 0; j < 4; ++j) {
            a0 = fmaf(vv[j], blo(uu[j].x), a0);
            a1 = fmaf(vv[j], bhi(uu[j].x), a1);
            a2 = fmaf(vv[j], blo(uu[j].y), a2);
            a3 = fmaf(vv[j], bhi(uu[j].y), a3);
        }
        e += 4;
    }
    for (; e < end; ++e) {
        int c = col[e]; float v = val[e];
        uint2 u = *(const uint2*)(yt + (size_t)c * 128);
        a0 = fmaf(v, blo(u.x), a0); a1 = fmaf(v, bhi(u.x), a1);
        a2 = fmaf(v, blo(u.y), a2); a3 = fmaf(v, bhi(u.y), a3);
    }
    float dd = dis[d];
    float d2 = dd * dd;
    uint2 us = *(const uint2*)(yt + (size_t)d * 128);
    float r0 = fmaf(dd, a0, d2 * blo(us.x));
    float r1 = fmaf(dd, a1, d2 * bhi(us.x));
    float r2 = fmaf(dd, a2, d2 * blo(us.y));
    float r3 = fmaf(dd, a3, d2 * bhi(us.y));
    if (FINAL) {
        float4 C1 = *(const float4*)(c1 + 4 * t);
        float4 C2 = *(const float4*)(c2 + 4 * t);
        float4 C3 = *(const float4*)(c3 + 4 * t);
        float4 C4 = *(const float4*)(c4 + 4 * t);
        float S1 = s1[d], S2 = s2[d], S3 = s3[d];
        r0 += S3 * C1.x + S2 * C2.x + S1 * C3.x + C4.x;
        r1 += S3 * C1.y + S2 * C2.y + S1 * C3.y + C4.y;
        r2 += S3 * C1.z + S2 * C2.z + S1 * C3.z + C4.z;
        r3 += S3 * C1.w + S2 * C2.w + S1 * C3.w + C4.w;
    }
    uint2 o;
    o.x = pack2(r0, r1);
    o.y = pack2(r2, r3);
    *(uint2*)(out + (size_t)d * 128 + 2 * t) = o;
}

// ---------------------------------------------------------------------------
// final layer: Y[M,16](f32) = relu(A[M,256](bf16)) @ W2[256,16](f32)
// ---------------------------------------------------------------------------
__global__ __launch_bounds__(256) void k_gemm16b(const uint* __restrict__ A,
                                                 const float* __restrict__ W2,
                                                 float* __restrict__ Y, int M) {
    __shared__ float Ws[256][16];
    int t = threadIdx.x;
    for (int i = t; i < 256 * 16; i += 256) Ws[i >> 4][i & 15] = W2[i];
    __syncthreads();
    int tx = t & 15, ty = t >> 4;
    int r = blockIdx.x * 16 + ty;
    if (r >= M) return;
    const uint* a = A + (size_t)r * 128;
    float acc = 0.f;
    for (int i = 0; i < 128; i += 4) {
        uint4 u = *(const uint4*)(a + i);
        float f;
        f = fmaxf(blo(u.x), 0.f); acc = fmaf(f, Ws[2 * i + 0][tx], acc);
        f = fmaxf(bhi(u.x), 0.f); acc = fmaf(f, Ws[2 * i + 1][tx], acc);
        f = fmaxf(blo(u.y), 0.f); acc = fmaf(f, Ws[2 * i + 2][tx], acc);
        f = fmaxf(bhi(u.y), 0.f); acc = fmaf(f, Ws[2 * i + 3][tx], acc);
        f = fmaxf(blo(u.z), 0.f); acc = fmaf(f, Ws[2 * i + 4][tx], acc);
        f = fmaxf(bhi(u.z), 0.f); acc = fmaf(f, Ws[2 * i + 5][tx], acc);
        f = fmaxf(blo(u.w), 0.f); acc = fmaf(f, Ws[2 * i + 6][tx], acc);
        f = fmaxf(bhi(u.w), 0.f); acc = fmaf(f, Ws[2 * i + 7][tx], acc);
    }
    Y[(size_t)r * NCLS + tx] = acc;
}

// propagation at width 16 (fp32)
__global__ __launch_bounds__(256) void k_agg16(const float* __restrict__ y16,
                                               const int* __restrict__ rowptr,
                                               const int* __restrict__ col,
                                               const float* __restrict__ val,
                                               const float* __restrict__ dis,
                                               const float* __restrict__ b2,
                                               float* __restrict__ out, int Nn) {
    int t = threadIdx.x;
    int tx = t & 15, ty = t >> 4;
    int d = blockIdx.x * 16 + ty;
    if (d >= Nn) return;
    int beg = rowptr[d], end = rowptr[d + 1];
    float acc = 0.f;
    for (int e = beg; e < end; ++e)
        acc = fmaf(val[e], y16[(size_t)col[e] * NCLS + tx], acc);
    float dd = dis[d];
    out[(size_t)d * NCLS + tx] = dd * acc + dd * dd * y16[(size_t)d * NCLS + tx] + b2[tx];
}

// ---------------------------------------------------------------------------
// softmax over axis 0
// ---------------------------------------------------------------------------
__global__ __launch_bounds__(256) void k_sm1(const float* __restrict__ z,
                                             float* __restrict__ pmax,
                                             float* __restrict__ psum, int Nn) {
    int b = blockIdx.x, t = threadIdx.x, tx = t & 15, ty = t >> 4;
    int CH = (Nn + 255) / 256;
    int r0 = b * CH, r1 = min(r0 + CH, Nn);
    __shared__ float red[16][17];
    __shared__ float gloc[16];
    float m = -3.4e38f;
    for (int r = r0 + ty; r < r1; r += 16) m = fmaxf(m, z[(size_t)r * NCLS + tx]);
    red[ty][tx] = m;
    __syncthreads();
    if (ty == 0) {
        float mm = red[0][tx];
#pragma unroll
        for (int i = 1; i < 16; ++i) mm = fmaxf(mm, red[i][tx]);
        gloc[tx] = mm;
    }
    __syncthreads();
    float g = gloc[tx];
    float s = 0.f;
    for (int r = r0 + ty; r < r1; r += 16) s += expf(z[(size_t)r * NCLS + tx] - g);
    red[ty][tx] = s;
    __syncthreads();
    if (ty == 0) {
        float ss = red[0][tx];
#pragma unroll
        for (int i = 1; i < 16; ++i) ss += red[i][tx];
        pmax[b * 16 + tx] = g;
        psum[b * 16 + tx] = ss;
    }
}

__global__ __launch_bounds__(256) void k_sm2(const float* __restrict__ pmax,
                                             const float* __restrict__ psum,
                                             float* __restrict__ g16,
                                             float* __restrict__ inv16) {
    int t = threadIdx.x, tx = t & 15, ty = t >> 4;
    __shared__ float red[16][17];
    __shared__ float gsh[16];
    float m = -3.4e38f;
    for (int b = ty; b < 256; b += 16) m = fmaxf(m, pmax[b * 16 + tx]);
    red[ty][tx] = m;
    __syncthreads();
    if (ty == 0) {
        float mm = red[0][tx];
#pragma unroll
        for (int i = 1; i < 16; ++i) mm = fmaxf(mm, red[i][tx]);
        gsh[tx] = mm;
    }
    __syncthreads();
    float g = gsh[tx];
    float s = 0.f;
    for (int b = ty; b < 256; b += 16)
        s += psum[b * 16 + tx] * expf(pmax[b * 16 + tx] - g);
    red[ty][tx] = s;
    __syncthreads();
    if (ty == 0) {
        float ss = red[0][tx];
#pragma unroll
        for (int i = 1; i < 16; ++i) ss += red[i][tx];
        g16[tx] = g;
        inv16[tx] = 1.0f / ss;
    }
}

__global__ void k_sm5(float* __restrict__ z, const float* __restrict__ g16,
                      const float* __restrict__ inv16, int total) {
    int i = blockIdx.x * 256 + threadIdx.x;
    if (i < total) {
        int c = i & 15;
        z[i] = expf(z[i] - g16[c]) * inv16[c];
    }
}

// ---------------------------------------------------------------------------
extern "C" void kernel_launch(void* const* d_in, const int* in_sizes, int n_in,
                              void* d_out, int out_size, void* d_ws, size_t ws_size,
                              hipStream_t stream) {
    const float* x  = (const float*)d_in[0];
    const int*   ei = (const int*)d_in[1];
    const float* W1 = (const float*)d_in[2];
    const float* b1 = (const float*)d_in[3];
    const float* Wi = (const float*)d_in[4];
    const float* bi = (const float*)d_in[5];
    const float* W2 = (const float*)d_in[6];
    const float* b2 = (const float*)d_in[7];
    float* out = (float*)d_out;

    int Nn = in_sizes[0] / NFEAT;   // 100000
    int E  = in_sizes[1] / 2;       // 1600000
    int nb = (Nn + 255) >> 8;       // 391 coarse buckets
    const int* esrc = ei;
    const int* edst = ei + E;

    char* p = (char*)d_ws;
    auto carve = [&](size_t bytes) -> char* {
        char* r = p;
        p += (bytes + 255) / 256 * 256;
        return r;
    };
    uint*  bufA    = (uint*) carve((size_t)Nn * 128 * 4);   // bf16 features
    uint*  bufB    = (uint*) carve((size_t)Nn * 128 * 4);
    uint*  xb      = (uint*) carve((size_t)Nn * 128 * 4);   // bf16 x
    int*   rowptr  = (int*)  carve((size_t)(Nn + 1) * 4);
    float* dis     = (float*)carve((size_t)Nn * 4);
    int*   csr_col = (int*)  carve((size_t)E * 4);
    float* csr_val = (float*)carve((size_t)E * 4);
    uint2* ebuf    = (uint2*)carve((size_t)E * 8);
    int*   bhist   = (int*)  carve(512 * 4);
    int*   boff    = (int*)  carve(512 * 4);
    int*   gcur    = (int*)  carve(512 * 4);
    float* y16     = (float*)carve((size_t)Nn * NCLS * 4);
    float* s1      = (float*)carve((size_t)Nn * 4);
    float* s2      = (float*)carve((size_t)Nn * 4);
    float* s3      = (float*)carve((size_t)Nn * 4);
    float* WA      = (float*)carve(256 * 256 * 4);
    float* WB      = (float*)carve(256 * 256 * 4);
    float* Wc      = (float*)carve(256 * 256 * 4);
    uint*  Wp      = (uint*) carve(32768 * 4);
    float* c1      = (float*)carve(256 * 4);
    float* c2      = (float*)carve(256 * 4);
    float* c3      = (float*)carve(256 * 4);
    float* u1      = (float*)carve(256 * 4);
    float* u2      = (float*)carve(256 * 4);
    float* pmax    = (float*)carve(256 * 16 * 4);
    float* psum    = (float*)carve(256 * 16 * 4);
    float* g16     = (float*)carve(16 * 4);
    float* inv16   = (float*)carve(16 * 4);

    hipMemsetAsync(bhist, 0, 512 * 4, stream);

    int gE = (E + 255) / 256;
    int gN = (Nn + 255) / 256;
    int nch = (E + 4095) / 4096;

    // graph build (bucketed counting sort)
    k_ccount<<<1024, 256, 0, stream>>>(edst, bhist, E, nb);
    k_cscan<<<1, 256, 0, stream>>>(bhist, boff, gcur, rowptr, nb, Nn);
    k_cfill<<<nch, 256, 0, stream>>>(esrc, edst, gcur, ebuf, E, nb);
    k_rowbuild<<<nb, 256, 0, stream>>>(ebuf, boff, rowptr, dis, csr_col, Nn, nb);
    k_val<<<gE, 256, 0, stream>>>(csr_col, dis, csr_val, E);

    // x -> bf16
    int total8 = Nn * 32;   // Nn*256/8
    k_tobf<<<(total8 + 255) / 256, 256, 0, stream>>>(x, xb, total8);

    // weight chain: Wc = W1 Wi^3 ; c1 = b1 Wi^3, c2 = bi Wi^2, c3 = bi Wi, c4 = bi
    k_mm256<<<256, 256, 0, stream>>>(W1, Wi, WA);
    k_mm256<<<256, 256, 0, stream>>>(WA, Wi, WB);
    k_mm256<<<256, 256, 0, stream>>>(WB, Wi, Wc);
    k_pack<<<128, 256, 0, stream>>>(Wc, Wp);
    k_vm256<<<1, 256, 0, stream>>>(bi, Wi, c3);
    k_vm256<<<1, 256, 0, stream>>>(c3, Wi, c2);
    k_vm256<<<1, 256, 0, stream>>>(b1, Wi, u1);
    k_vm256<<<1, 256, 0, stream>>>(u1, Wi, u2);
    k_vm256<<<1, 256, 0, stream>>>(u2, Wi, c1);

    // scalar propagation vectors s1 = A1, s2 = A^2 1, s3 = A^3 1
    k_svec<1><<<gN, 256, 0, stream>>>(nullptr, rowptr, csr_col, csr_val, dis, s1, Nn);
    k_svec<0><<<gN, 256, 0, stream>>>(s1, rowptr, csr_col, csr_val, dis, s2, Nn);
    k_svec<0><<<gN, 256, 0, stream>>>(s2, rowptr, csr_col, csr_val, dis, s3, Nn);

    // y0 = x @ Wc  (bf16 in/out, MFMA; 2-way col split for occupancy)
    dim3 gg((Nn + 63) / 64, 2);
    gemm_mfma<<<gg, 256, 0, stream>>>(xb, Wp, (ushort*)bufB, Nn);

    // h4 = A^4 y0 + rank-1 terms (in the last pass)
    int gA = (Nn + 3) / 4;
    k_aggb<0><<<gA, 256, 0, stream>>>(bufB, rowptr, csr_col, csr_val, dis,
                                      nullptr, nullptr, nullptr, nullptr, nullptr, nullptr, nullptr, bufA, Nn);
    k_aggb<0><<<gA, 256, 0, stream>>>(bufA, rowptr, csr_col, csr_val, dis,
                                      nullptr, nullptr, nullptr, nullptr, nullptr, nullptr, nullptr, bufB, Nn);
    k_aggb<0><<<gA, 256, 0, stream>>>(bufB, rowptr, csr_col, csr_val, dis,
                                      nullptr, nullptr, nullptr, nullptr, nullptr, nullptr, nullptr, bufA, Nn);
    k_aggb<1><<<gA, 256, 0, stream>>>(bufA, rowptr, csr_col, csr_val, dis,
                                      s1, s2, s3, c1, c2, c3, bi, bufB, Nn);

    // final: z = A(relu(h4) W2) + b2 ; softmax over nodes
    int g16b = (Nn + 15) / 16;
    k_gemm16b<<<g16b, 256, 0, stream>>>(bufB, W2, y16, Nn);
    k_agg16<<<g16b, 256, 0, stream>>>(y16, rowptr, csr_col, csr_val, dis, b2, out, Nn);

    k_sm1<<<256, 256, 0, stream>>>(out, pmax, psum, Nn);
    k_sm2<<<1, 256, 0, stream>>>(pmax, psum, g16, inv16);
    k_sm5<<<(Nn * NCLS + 255) / 256, 256, 0, stream>>>(out, g16, inv16, Nn * NCLS);
}

// Round 8
// 840.950 us; speedup vs baseline: 1.0924x; 1.0740x over previous
//
#include <hip/hip_runtime.h>
#include <cstdint>
#include <cstddef>

#define NFEAT 256
#define NCLS  16

typedef unsigned int uint;
typedef unsigned short ushort;
typedef __attribute__((ext_vector_type(8))) short short8;
typedef __attribute__((ext_vector_type(4))) float f32x4;

__device__ inline float blo(uint u) { return __uint_as_float(u << 16); }
__device__ inline float bhi(uint u) { return __uint_as_float(u & 0xffff0000u); }
__device__ inline ushort f2bf(float f) {
    uint b = __float_as_uint(f);
    b += 0x7fffu + ((b >> 16) & 1u);
    return (ushort)(b >> 16);
}
__device__ inline uint pack2(float a, float b) {
    return (uint)f2bf(a) | ((uint)f2bf(b) << 16);
}

// ---------------------------------------------------------------------------
// Graph build: bucketed counting sort (bucket = dst >> 8, 391 buckets)
// ---------------------------------------------------------------------------
__global__ __launch_bounds__(256) void k_ccount(const int* __restrict__ dst,
                                                int* __restrict__ bhist, int E, int nb) {
    __shared__ int h[512];
    int t = threadIdx.x;
    for (int i = t; i < nb; i += 256) h[i] = 0;
    __syncthreads();
    for (int i = blockIdx.x * 256 + t; i < E; i += gridDim.x * 256)
        atomicAdd(&h[dst[i] >> 8], 1);
    __syncthreads();
    for (int i = t; i < nb; i += 256)
        if (h[i]) atomicAdd(&bhist[i], h[i]);
}

__global__ __launch_bounds__(256) void k_cscan(const int* __restrict__ bhist,
                                               int* __restrict__ boff,
                                               int* __restrict__ gcur,
                                               int* __restrict__ rowptr,
                                               int nb, int Nn) {
    int t = threadIdx.x;
    int v0 = (2 * t < nb) ? bhist[2 * t] : 0;
    int v1 = (2 * t + 1 < nb) ? bhist[2 * t + 1] : 0;
    int s = v0 + v1;
    __shared__ int ps[256];
    ps[t] = s;
    __syncthreads();
    for (int off = 1; off < 256; off <<= 1) {
        int v = (t >= off) ? ps[t - off] : 0;
        __syncthreads();
        ps[t] += v;
        __syncthreads();
    }
    int ex = ps[t] - s;
    if (2 * t < nb)     { boff[2 * t] = ex;          gcur[2 * t] = ex; }
    if (2 * t + 1 < nb) { boff[2 * t + 1] = ex + v0; gcur[2 * t + 1] = ex + v0; }
    if (t == 255) { boff[nb] = ps[255]; rowptr[Nn] = ps[255]; }
}

__global__ __launch_bounds__(256) void k_cfill(const int* __restrict__ src,
                                               const int* __restrict__ dst,
                                               int* __restrict__ gcur,
                                               uint2* __restrict__ ebuf, int E, int nb) {
    __shared__ int hist[400];
    __shared__ int lstart[400];
    __shared__ int gbase[400];
    __shared__ int cur[400];
    __shared__ int ps[256];
    __shared__ uint2 stg[4096];
    __shared__ ushort sb[4096];
    int t = threadIdx.x;
    int base = blockIdx.x * 4096;
    int lim = min(4096, E - base);
    for (int i = t; i < nb; i += 256) hist[i] = 0;
    __syncthreads();
    for (int k = t; k < lim; k += 256) atomicAdd(&hist[dst[base + k] >> 8], 1);
    __syncthreads();
    int v0 = (2 * t < nb) ? hist[2 * t] : 0;
    int v1 = (2 * t + 1 < nb) ? hist[2 * t + 1] : 0;
    int s = v0 + v1;
    ps[t] = s;
    __syncthreads();
    for (int off = 1; off < 256; off <<= 1) {
        int v = (t >= off) ? ps[t - off] : 0;
        __syncthreads();
        ps[t] += v;
        __syncthreads();
    }
    int ex = ps[t] - s;
    if (2 * t < nb) {
        lstart[2 * t] = ex; cur[2 * t] = ex;
        if (v0) gbase[2 * t] = atomicAdd(&gcur[2 * t], v0);
    }
    if (2 * t + 1 < nb) {
        lstart[2 * t + 1] = ex + v0; cur[2 * t + 1] = ex + v0;
        if (v1) gbase[2 * t + 1] = atomicAdd(&gcur[2 * t + 1], v1);
    }
    __syncthreads();
    for (int k = t; k < lim; k += 256) {
        int s_ = src[base + k], d_ = dst[base + k];
        int b = d_ >> 8;
        int slot = atomicAdd(&cur[b], 1);
        stg[slot] = make_uint2((uint)s_, (uint)d_);
        sb[slot] = (ushort)b;
    }
    __syncthreads();
    for (int j = t; j < lim; j += 256) {
        int b = sb[j];
        ebuf[gbase[b] + (j - lstart[b])] = stg[j];
    }
}

__global__ __launch_bounds__(256) void k_rowbuild(const uint2* __restrict__ ebuf,
                                                  const int* __restrict__ boff,
                                                  int* __restrict__ rowptr,
                                                  float* __restrict__ dis,
                                                  int* __restrict__ csr_col,
                                                  int Nn, int nb) {
    int b = blockIdx.x;
    int t = threadIdx.x;
    int beg = boff[b], end = boff[b + 1];
    __shared__ int rcnt[256];
    __shared__ int rstart[256];
    __shared__ int ps[256];
    rcnt[t] = 0;
    __syncthreads();
    for (int e = beg + t; e < end; e += 256)
        atomicAdd(&rcnt[ebuf[e].y & 255], 1);
    __syncthreads();
    int v = rcnt[t];
    ps[t] = v;
    __syncthreads();
    for (int off = 1; off < 256; off <<= 1) {
        int u = (t >= off) ? ps[t - off] : 0;
        __syncthreads();
        ps[t] += u;
        __syncthreads();
    }
    int ex = ps[t] - v;
    int node = b * 256 + t;
    if (node < Nn) {
        rowptr[node] = beg + ex;
        dis[node] = rsqrtf((float)(v + 1));
    }
    rstart[t] = beg + ex;
    __syncthreads();
    rcnt[t] = 0;
    __syncthreads();
    for (int e = beg + t; e < end; e += 256) {
        uint2 ed = ebuf[e];
        int r = ed.y & 255;
        int slot = atomicAdd(&rcnt[r], 1);
        csr_col[rstart[r] + slot] = (int)ed.x;
    }
}

__global__ void k_val(const int* __restrict__ col, const float* __restrict__ dis,
                      float* __restrict__ val, int E) {
    int i = blockIdx.x * 256 + threadIdx.x;
    if (i < E) val[i] = dis[col[i]];
}

// ---------------------------------------------------------------------------
// weight chain helpers
// T = W1 @ Wi  (blocks 0..255) ; S = Wi @ Wi  (blocks 256..511)
// ---------------------------------------------------------------------------
__global__ __launch_bounds__(256) void k_mmTS(const float* __restrict__ W1,
                                              const float* __restrict__ Wi,
                                              float* __restrict__ T,
                                              float* __restrict__ S) {
    int b = blockIdx.x, j = threadIdx.x;
    if (b < 256) {
        float acc = 0.f;
        for (int k = 0; k < 256; ++k) acc = fmaf(W1[b * 256 + k], Wi[k * 256 + j], acc);
        T[b * 256 + j] = acc;
    } else {
        int i = b - 256;
        float acc = 0.f;
        for (int k = 0; k < 256; ++k) acc = fmaf(Wi[i * 256 + k], Wi[k * 256 + j], acc);
        S[i * 256 + j] = acc;
    }
}

__global__ __launch_bounds__(256) void k_mm256(const float* __restrict__ A,
                                               const float* __restrict__ B,
                                               float* __restrict__ C) {
    int i = blockIdx.x, j = threadIdx.x;
    float acc = 0.f;
    for (int k = 0; k < 256; ++k) acc = fmaf(A[i * 256 + k], B[k * 256 + j], acc);
    C[i * 256 + j] = acc;
}

// all 5 bias-vector chain steps in one block (bit-identical to prior k_vm256 seq)
__global__ __launch_bounds__(256) void k_vchain(const float* __restrict__ b1,
                                                const float* __restrict__ bi,
                                                const float* __restrict__ Wi,
                                                float* __restrict__ c1,
                                                float* __restrict__ c2,
                                                float* __restrict__ c3) {
    __shared__ float v[256];
    int t = threadIdx.x;
    float r;
    // b1 chain: u1 = b1 Wi ; u2 = u1 Wi ; c1 = u2 Wi
    v[t] = b1[t]; __syncthreads();
    r = 0.f; for (int k = 0; k < 256; ++k) r = fmaf(v[k], Wi[(size_t)k * 256 + t], r);
    __syncthreads(); v[t] = r; __syncthreads();
    r = 0.f; for (int k = 0; k < 256; ++k) r = fmaf(v[k], Wi[(size_t)k * 256 + t], r);
    __syncthreads(); v[t] = r; __syncthreads();
    r = 0.f; for (int k = 0; k < 256; ++k) r = fmaf(v[k], Wi[(size_t)k * 256 + t], r);
    c1[t] = r;
    // bi chain: c3 = bi Wi ; c2 = c3 Wi
    __syncthreads(); v[t] = bi[t]; __syncthreads();
    r = 0.f; for (int k = 0; k < 256; ++k) r = fmaf(v[k], Wi[(size_t)k * 256 + t], r);
    c3[t] = r;
    __syncthreads(); v[t] = r; __syncthreads();
    r = 0.f; for (int k = 0; k < 256; ++k) r = fmaf(v[k], Wi[(size_t)k * 256 + t], r);
    c2[t] = r;
}

// pack Wc (fp32 [256][256]) into MFMA B-fragment layout, bf16.
__global__ __launch_bounds__(256) void k_pack(const float* __restrict__ W,
                                              uint* __restrict__ Wp) {
    int idx = blockIdx.x * 256 + threadIdx.x;   // 32768 words
    int w = idx & 3, lane = (idx >> 2) & 63, kstep = (idx >> 8) & 7, n16 = idx >> 11;
    int n = n16 * 16 + (lane & 15);
    int k = kstep * 32 + (lane >> 4) * 8 + 2 * w;
    Wp[idx] = pack2(W[k * 256 + n], W[(k + 1) * 256 + n]);
}

// ---------------------------------------------------------------------------
// MFMA GEMM: C[M,256](bf16) = x[M,256](fp32, cvt on the fly) @ Wp(bf16 frags)
// block = 32 rows x 256 cols as 4 waves (2 row-groups x 2 col-halves), acc[8]
// A read exactly once from HBM (col-half duplicate hits L1/L2).
// ---------------------------------------------------------------------------
__global__ __launch_bounds__(256) void gemm_mfma(const float* __restrict__ A,
                                                 const uint* __restrict__ Wp,
                                                 ushort* __restrict__ C, int M) {
    int t = threadIdx.x;
    int wv = t >> 6;
    int l = t & 63;
    int wr = wv >> 1, wc = wv & 1;
    int m16 = l & 15;
    int kc = l >> 4;
    int bm = blockIdx.x * 32 + wr * 16;
    int n16b = wc * 8;                  // 8 n16-tiles = 128 cols
    int row = bm + m16;
    bool valid = row < M;
    const float* ap = A + (size_t)(valid ? row : 0) * 256 + kc * 8;
    const short8* wp = (const short8*)Wp;

    f32x4 acc[8];
#pragma unroll
    for (int n = 0; n < 8; ++n) acc[n] = {0.f, 0.f, 0.f, 0.f};

#pragma unroll
    for (int ks = 0; ks < 8; ++ks) {
        float4 fa0 = make_float4(0.f, 0.f, 0.f, 0.f), fa1 = fa0;
        if (valid) {
            fa0 = *(const float4*)(ap + ks * 32);
            fa1 = *(const float4*)(ap + ks * 32 + 4);
        }
        short8 a;
        a[0] = (short)f2bf(fa0.x); a[1] = (short)f2bf(fa0.y);
        a[2] = (short)f2bf(fa0.z); a[3] = (short)f2bf(fa0.w);
        a[4] = (short)f2bf(fa1.x); a[5] = (short)f2bf(fa1.y);
        a[6] = (short)f2bf(fa1.z); a[7] = (short)f2bf(fa1.w);
#pragma unroll
        for (int n = 0; n < 8; ++n) {
            short8 b = wp[((n16b + n) * 8 + ks) * 64 + l];
            acc[n] = __builtin_amdgcn_mfma_f32_16x16x32_bf16(a, b, acc[n], 0, 0, 0);
        }
    }

    // C/D layout: col = lane&15, row = (lane>>4)*4 + reg   [m89-verified]
#pragma unroll
    for (int r = 0; r < 4; ++r) {
        int orow = bm + kc * 4 + r;
        if (orow < M) {
            ushort* cp = C + (size_t)orow * 256 + n16b * 16 + m16;
#pragma unroll
            for (int n = 0; n < 8; ++n) cp[n * 16] = f2bf(acc[n][r]);
        }
    }
}

// scalar propagation: sout = A_hat * sin   (FIRST: sin == ones)
template <int FIRST>
__global__ __launch_bounds__(256) void k_svec(const float* __restrict__ sin,
                                              const int* __restrict__ rowptr,
                                              const int* __restrict__ col,
                                              const float* __restrict__ val,
                                              const float* __restrict__ dis,
                                              float* __restrict__ sout, int Nn) {
    int d = blockIdx.x * 256 + threadIdx.x;
    if (d >= Nn) return;
    int beg = rowptr[d], end = rowptr[d + 1];
    float acc = 0.f;
    if (FIRST) {
        for (int e = beg; e < end; ++e) acc += val[e];
    } else {
        for (int e = beg; e < end; ++e) acc = fmaf(val[e], sin[col[e]], acc);
    }
    float dd = dis[d];
    sout[d] = fmaf(dd, acc, dd * dd * (FIRST ? 1.f : sin[d]));
}

// ---------------------------------------------------------------------------
// bf16 propagation: out[d] = bf16( dis_d*sum(val*y[col]) + dis_d^2*y[d] [+rank1] )
// 256-thread blocks = 4 waves = 4 nodes; lane owns 4 features (uint2 = 8B);
// 8 edges in flight per wave.  [at pattern BW ceiling — do not touch]
// ---------------------------------------------------------------------------
template <int FINAL>
__global__ __launch_bounds__(256) void k_aggb(const uint* __restrict__ y,
                                              const int* __restrict__ rowptr,
                                              const int* __restrict__ col,
                                              const float* __restrict__ val,
                                              const float* __restrict__ dis,
                                              const float* __restrict__ s1,
                                              const float* __restrict__ s2,
                                              const float* __restrict__ s3,
                                              const float* __restrict__ c1,
                                              const float* __restrict__ c2,
                                              const float* __restrict__ c3,
                                              const float* __restrict__ c4,
                                              uint* __restrict__ out, int Nn) {
    int wid = threadIdx.x >> 6;
    int t = threadIdx.x & 63;
    int d = blockIdx.x * 4 + wid;
    if (d >= Nn) return;
    const uint* yt = y + 2 * t;
    int beg = rowptr[d], end = rowptr[d + 1];
    float a0 = 0.f, a1 = 0.f, a2 = 0.f, a3 = 0.f;
    int e = beg;
    for (; e + 7 < end; e += 8) {
        int cc[8]; float vv[8]; uint2 uu[8];
#pragma unroll
        for (int j = 0; j < 8; ++j) { cc[j] = col[e + j]; vv[j] = val[e + j]; }
#pragma unroll
        for (int j = 0; j < 8; ++j) uu[j] = *(const uint2*)(yt + (size_t)cc[j] * 128);
#pragma unroll
        for (int j = 0; j < 8; ++j) {
            a0 = fmaf(vv[j], blo(uu[j].x), a0);
            a1 = fmaf(vv[j], bhi(uu[j].x), a1);
            a2 = fmaf(vv[j], blo(uu[j].y), a2);
            a3 = fmaf(vv[j], bhi(uu[j].y), a3);
        }
    }
    if (e + 3 < end) {
        int cc[4]; float vv[4]; uint2 uu[4];
#pragma unroll
        for (int j = 0; j < 4; ++j) { cc[j] = col[e + j]; vv[j] = val[e + j]; }
#pragma unroll
        for (int j = 0; j < 4; ++j) uu[j] = *(const uint2*)(yt + (size_t)cc[j] * 128);
#pragma unroll
        for (int j = 0; j < 4; ++j) {
            a0 = fmaf(vv[j], blo(uu[j].x), a0);
            a1 = fmaf(vv[j], bhi(uu[j].x), a1);
            a2 = fmaf(vv[j], blo(uu[j].y), a2);
            a3 = fmaf(vv[j], bhi(uu[j].y), a3);
        }
        e += 4;
    }
    for (; e < end; ++e) {
        int c = col[e]; float v = val[e];
        uint2 u = *(const uint2*)(yt + (size_t)c * 128);
        a0 = fmaf(v, blo(u.x), a0); a1 = fmaf(v, bhi(u.x), a1);
        a2 = fmaf(v, blo(u.y), a2); a3 = fmaf(v, bhi(u.y), a3);
    }
    float dd = dis[d];
    float d2 = dd * dd;
    uint2 us = *(const uint2*)(yt + (size_t)d * 128);
    float r0 = fmaf(dd, a0, d2 * blo(us.x));
    float r1 = fmaf(dd, a1, d2 * bhi(us.x));
    float r2 = fmaf(dd, a2, d2 * blo(us.y));
    float r3 = fmaf(dd, a3, d2 * bhi(us.y));
    if (FINAL) {
        float4 C1 = *(const float4*)(c1 + 4 * t);
        float4 C2 = *(const float4*)(c2 + 4 * t);
        float4 C3 = *(const float4*)(c3 + 4 * t);
        float4 C4 = *(const float4*)(c4 + 4 * t);
        float S1 = s1[d], S2 = s2[d], S3 = s3[d];
        r0 += S3 * C1.x + S2 * C2.x + S1 * C3.x + C4.x;
        r1 += S3 * C1.y + S2 * C2.y + S1 * C3.y + C4.y;
        r2 += S3 * C1.z + S2 * C2.z + S1 * C3.z + C4.z;
        r3 += S3 * C1.w + S2 * C2.w + S1 * C3.w + C4.w;
    }
    uint2 o;
    o.x = pack2(r0, r1);
    o.y = pack2(r2, r3);
    *(uint2*)(out + (size_t)d * 128 + 2 * t) = o;
}

// ---------------------------------------------------------------------------
// final layer: Y[M,16](f32) = relu(A[M,256](bf16)) @ W2[256,16](f32)
// ---------------------------------------------------------------------------
__global__ __launch_bounds__(256) void k_gemm16b(const uint* __restrict__ A,
                                                 const float* __restrict__ W2,
                                                 float* __restrict__ Y, int M) {
    __shared__ float Ws[256][16];
    int t = threadIdx.x;
    for (int i = t; i < 256 * 16; i += 256) Ws[i >> 4][i & 15] = W2[i];
    __syncthreads();
    int tx = t & 15, ty = t >> 4;
    int r = blockIdx.x * 16 + ty;
    if (r >= M) return;
    const uint* a = A + (size_t)r * 128;
    float acc = 0.f;
    for (int i = 0; i < 128; i += 4) {
        uint4 u = *(const uint4*)(a + i);
        float f;
        f = fmaxf(blo(u.x), 0.f); acc = fmaf(f, Ws[2 * i + 0][tx], acc);
        f = fmaxf(bhi(u.x), 0.f); acc = fmaf(f, Ws[2 * i + 1][tx], acc);
        f = fmaxf(blo(u.y), 0.f); acc = fmaf(f, Ws[2 * i + 2][tx], acc);
        f = fmaxf(bhi(u.y), 0.f); acc = fmaf(f, Ws[2 * i + 3][tx], acc);
        f = fmaxf(blo(u.z), 0.f); acc = fmaf(f, Ws[2 * i + 4][tx], acc);
        f = fmaxf(bhi(u.z), 0.f); acc = fmaf(f, Ws[2 * i + 5][tx], acc);
        f = fmaxf(blo(u.w), 0.f); acc = fmaf(f, Ws[2 * i + 6][tx], acc);
        f = fmaxf(bhi(u.w), 0.f); acc = fmaf(f, Ws[2 * i + 7][tx], acc);
    }
    Y[(size_t)r * NCLS + tx] = acc;
}

// propagation at width 16 (fp32)
__global__ __launch_bounds__(256) void k_agg16(const float* __restrict__ y16,
                                               const int* __restrict__ rowptr,
                                               const int* __restrict__ col,
                                               const float* __restrict__ val,
                                               const float* __restrict__ dis,
                                               const float* __restrict__ b2,
                                               float* __restrict__ out, int Nn) {
    int t = threadIdx.x;
    int tx = t & 15, ty = t >> 4;
    int d = blockIdx.x * 16 + ty;
    if (d >= Nn) return;
    int beg = rowptr[d], end = rowptr[d + 1];
    float acc = 0.f;
    for (int e = beg; e < end; ++e)
        acc = fmaf(val[e], y16[(size_t)col[e] * NCLS + tx], acc);
    float dd = dis[d];
    out[(size_t)d * NCLS + tx] = dd * acc + dd * dd * y16[(size_t)d * NCLS + tx] + b2[tx];
}

// ---------------------------------------------------------------------------
// softmax over axis 0
// ---------------------------------------------------------------------------
__global__ __launch_bounds__(256) void k_sm1(const float* __restrict__ z,
                                             float* __restrict__ pmax,
                                             float* __restrict__ psum, int Nn) {
    int b = blockIdx.x, t = threadIdx.x, tx = t & 15, ty = t >> 4;
    int CH = (Nn + 255) / 256;
    int r0 = b * CH, r1 = min(r0 + CH, Nn);
    __shared__ float red[16][17];
    __shared__ float gloc[16];
    float m = -3.4e38f;
    for (int r = r0 + ty; r < r1; r += 16) m = fmaxf(m, z[(size_t)r * NCLS + tx]);
    red[ty][tx] = m;
    __syncthreads();
    if (ty == 0) {
        float mm = red[0][tx];
#pragma unroll
        for (int i = 1; i < 16; ++i) mm = fmaxf(mm, red[i][tx]);
        gloc[tx] = mm;
    }
    __syncthreads();
    float g = gloc[tx];
    float s = 0.f;
    for (int r = r0 + ty; r < r1; r += 16) s += expf(z[(size_t)r * NCLS + tx] - g);
    red[ty][tx] = s;
    __syncthreads();
    if (ty == 0) {
        float ss = red[0][tx];
#pragma unroll
        for (int i = 1; i < 16; ++i) ss += red[i][tx];
        pmax[b * 16 + tx] = g;
        psum[b * 16 + tx] = ss;
    }
}

__global__ __launch_bounds__(256) void k_sm2(const float* __restrict__ pmax,
                                             const float* __restrict__ psum,
                                             float* __restrict__ g16,
                                             float* __restrict__ inv16) {
    int t = threadIdx.x, tx = t & 15, ty = t >> 4;
    __shared__ float red[16][17];
    __shared__ float gsh[16];
    float m = -3.4e38f;
    for (int b = ty; b < 256; b += 16) m = fmaxf(m, pmax[b * 16 + tx]);
    red[ty][tx] = m;
    __syncthreads();
    if (ty == 0) {
        float mm = red[0][tx];
#pragma unroll
        for (int i = 1; i < 16; ++i) mm = fmaxf(mm, red[i][tx]);
        gsh[tx] = mm;
    }
    __syncthreads();
    float g = gsh[tx];
    float s = 0.f;
    for (int b = ty; b < 256; b += 16)
        s += psum[b * 16 + tx] * expf(pmax[b * 16 + tx] - g);
    red[ty][tx] = s;
    __syncthreads();
    if (ty == 0) {
        float ss = red[0][tx];
#pragma unroll
        for (int i = 1; i < 16; ++i) ss += red[i][tx];
        g16[tx] = g;
        inv16[tx] = 1.0f / ss;
    }
}

__global__ void k_sm5(float* __restrict__ z, const float* __restrict__ g16,
                      const float* __restrict__ inv16, int total) {
    int i = blockIdx.x * 256 + threadIdx.x;
    if (i < total) {
        int c = i & 15;
        z[i] = expf(z[i] - g16[c]) * inv16[c];
    }
}

// ---------------------------------------------------------------------------
extern "C" void kernel_launch(void* const* d_in, const int* in_sizes, int n_in,
                              void* d_out, int out_size, void* d_ws, size_t ws_size,
                              hipStream_t stream) {
    const float* x  = (const float*)d_in[0];
    const int*   ei = (const int*)d_in[1];
    const float* W1 = (const float*)d_in[2];
    const float* b1 = (const float*)d_in[3];
    const float* Wi = (const float*)d_in[4];
    const float* bi = (const float*)d_in[5];
    const float* W2 = (const float*)d_in[6];
    const float* b2 = (const float*)d_in[7];
    float* out = (float*)d_out;

    int Nn = in_sizes[0] / NFEAT;   // 100000
    int E  = in_sizes[1] / 2;       // 1600000
    int nb = (Nn + 255) >> 8;       // 391 coarse buckets
    const int* esrc = ei;
    const int* edst = ei + E;

    char* p = (char*)d_ws;
    auto carve = [&](size_t bytes) -> char* {
        char* r = p;
        p += (bytes + 255) / 256 * 256;
        return r;
    };
    uint*  bufA    = (uint*) carve((size_t)Nn * 128 * 4);   // bf16 features
    uint*  bufB    = (uint*) carve((size_t)Nn * 128 * 4);
    int*   rowptr  = (int*)  carve((size_t)(Nn + 1) * 4);
    float* dis     = (float*)carve((size_t)Nn * 4);
    int*   csr_col = (int*)  carve((size_t)E * 4);
    float* csr_val = (float*)carve((size_t)E * 4);
    uint2* ebuf    = (uint2*)carve((size_t)E * 8);
    int*   bhist   = (int*)  carve(512 * 4);
    int*   boff    = (int*)  carve(512 * 4);
    int*   gcur    = (int*)  carve(512 * 4);
    float* y16     = (float*)carve((size_t)Nn * NCLS * 4);
    float* s1      = (float*)carve((size_t)Nn * 4);
    float* s2      = (float*)carve((size_t)Nn * 4);
    float* s3      = (float*)carve((size_t)Nn * 4);
    float* WA      = (float*)carve(256 * 256 * 4);   // T = W1 Wi
    float* WB      = (float*)carve(256 * 256 * 4);   // S = Wi Wi
    float* Wc      = (float*)carve(256 * 256 * 4);   // Wc = T S = W1 Wi^3
    uint*  Wp      = (uint*) carve(32768 * 4);
    float* c1      = (float*)carve(256 * 4);
    float* c2      = (float*)carve(256 * 4);
    float* c3      = (float*)carve(256 * 4);
    float* pmax    = (float*)carve(256 * 16 * 4);
    float* psum    = (float*)carve(256 * 16 * 4);
    float* g16     = (float*)carve(16 * 4);
    float* inv16   = (float*)carve(16 * 4);

    hipMemsetAsync(bhist, 0, 512 * 4, stream);

    int gE = (E + 255) / 256;
    int gN = (Nn + 255) / 256;
    int nch = (E + 4095) / 4096;

    // graph build (bucketed counting sort)
    k_ccount<<<1024, 256, 0, stream>>>(edst, bhist, E, nb);
    k_cscan<<<1, 256, 0, stream>>>(bhist, boff, gcur, rowptr, nb, Nn);
    k_cfill<<<nch, 256, 0, stream>>>(esrc, edst, gcur, ebuf, E, nb);
    k_rowbuild<<<nb, 256, 0, stream>>>(ebuf, boff, rowptr, dis, csr_col, Nn, nb);
    k_val<<<gE, 256, 0, stream>>>(csr_col, dis, csr_val, E);

    // weight chain (3 launches): {T, S} ; Wc = T S ; bias vectors
    k_mmTS<<<512, 256, 0, stream>>>(W1, Wi, WA, WB);
    k_mm256<<<256, 256, 0, stream>>>(WA, WB, Wc);
    k_pack<<<128, 256, 0, stream>>>(Wc, Wp);
    k_vchain<<<1, 256, 0, stream>>>(b1, bi, Wi, c1, c2, c3);

    // scalar propagation vectors s1 = A1, s2 = A^2 1, s3 = A^3 1
    k_svec<1><<<gN, 256, 0, stream>>>(nullptr, rowptr, csr_col, csr_val, dis, s1, Nn);
    k_svec<0><<<gN, 256, 0, stream>>>(s1, rowptr, csr_col, csr_val, dis, s2, Nn);
    k_svec<0><<<gN, 256, 0, stream>>>(s2, rowptr, csr_col, csr_val, dis, s3, Nn);

    // y0 = x @ Wc  (fp32 in, bf16 out, MFMA; A read once)
    gemm_mfma<<<(Nn + 31) / 32, 256, 0, stream>>>(x, Wp, (ushort*)bufB, Nn);

    // h4 = A^4 y0 + rank-1 terms (in the last pass)
    int gA = (Nn + 3) / 4;
    k_aggb<0><<<gA, 256, 0, stream>>>(bufB, rowptr, csr_col, csr_val, dis,
                                      nullptr, nullptr, nullptr, nullptr, nullptr, nullptr, nullptr, bufA, Nn);
    k_aggb<0><<<gA, 256, 0, stream>>>(bufA, rowptr, csr_col, csr_val, dis,
                                      nullptr, nullptr, nullptr, nullptr, nullptr, nullptr, nullptr, bufB, Nn);
    k_aggb<0><<<gA, 256, 0, stream>>>(bufB, rowptr, csr_col, csr_val, dis,
                                      nullptr, nullptr, nullptr, nullptr, nullptr, nullptr, nullptr, bufA, Nn);
    k_aggb<1><<<gA, 256, 0, stream>>>(bufA, rowptr, csr_col, csr_val, dis,
                                      s1, s2, s3, c1, c2, c3, bi, bufB, Nn);

    // final: z = A(relu(h4) W2) + b2 ; softmax over nodes
    int g16b = (Nn + 15) / 16;
    k_gemm16b<<<g16b, 256, 0, stream>>>(bufB, W2, y16, Nn);
    k_agg16<<<g16b, 256, 0, stream>>>(y16, rowptr, csr_col, csr_val, dis, b2, out, Nn);

    k_sm1<<<256, 256, 0, stream>>>(out, pmax, psum, Nn);
    k_sm2<<<1, 256, 0, stream>>>(pmax, psum, g16, inv16);
    k_sm5<<<(Nn * NCLS + 255) / 256, 256, 0, stream>>>(out, g16, inv16, Nn * NCLS);
}

// Round 9
// 822.097 us; speedup vs baseline: 1.1175x; 1.0229x over previous
//
#include <hip/hip_runtime.h>
#include <cstdint>
#include <cstddef>

#define NFEAT 256
#define NCLS  16

typedef unsigned int uint;
typedef unsigned short ushort;
typedef __attribute__((ext_vector_type(8))) short short8;
typedef __attribute__((ext_vector_type(4))) float f32x4;

__device__ inline float blo(uint u) { return __uint_as_float(u << 16); }
__device__ inline float bhi(uint u) { return __uint_as_float(u & 0xffff0000u); }
__device__ inline ushort f2bf(float f) {
    uint b = __float_as_uint(f);
    b += 0x7fffu + ((b >> 16) & 1u);
    return (ushort)(b >> 16);
}
__device__ inline uint pack2(float a, float b) {
    return (uint)f2bf(a) | ((uint)f2bf(b) << 16);
}

// ---------------------------------------------------------------------------
// Graph build: bucketed counting sort (bucket = dst >> 8, 391 buckets)
// ---------------------------------------------------------------------------
__global__ __launch_bounds__(256) void k_ccount(const int* __restrict__ dst,
                                                int* __restrict__ bhist, int E, int nb) {
    __shared__ int h[512];
    int t = threadIdx.x;
    for (int i = t; i < nb; i += 256) h[i] = 0;
    __syncthreads();
    for (int i = blockIdx.x * 256 + t; i < E; i += gridDim.x * 256)
        atomicAdd(&h[dst[i] >> 8], 1);
    __syncthreads();
    for (int i = t; i < nb; i += 256)
        if (h[i]) atomicAdd(&bhist[i], h[i]);
}

__global__ __launch_bounds__(256) void k_cscan(const int* __restrict__ bhist,
                                               int* __restrict__ boff,
                                               int* __restrict__ gcur,
                                               int* __restrict__ rowptr,
                                               int nb, int Nn) {
    int t = threadIdx.x;
    int v0 = (2 * t < nb) ? bhist[2 * t] : 0;
    int v1 = (2 * t + 1 < nb) ? bhist[2 * t + 1] : 0;
    int s = v0 + v1;
    __shared__ int ps[256];
    ps[t] = s;
    __syncthreads();
    for (int off = 1; off < 256; off <<= 1) {
        int v = (t >= off) ? ps[t - off] : 0;
        __syncthreads();
        ps[t] += v;
        __syncthreads();
    }
    int ex = ps[t] - s;
    if (2 * t < nb)     { boff[2 * t] = ex;          gcur[2 * t] = ex; }
    if (2 * t + 1 < nb) { boff[2 * t + 1] = ex + v0; gcur[2 * t + 1] = ex + v0; }
    if (t == 255) { boff[nb] = ps[255]; rowptr[Nn] = ps[255]; }
}

__global__ __launch_bounds__(256) void k_cfill(const int* __restrict__ src,
                                               const int* __restrict__ dst,
                                               int* __restrict__ gcur,
                                               uint2* __restrict__ ebuf, int E, int nb) {
    __shared__ int hist[400];
    __shared__ int lstart[400];
    __shared__ int gbase[400];
    __shared__ int cur[400];
    __shared__ int ps[256];
    __shared__ uint2 stg[4096];
    __shared__ ushort sb[4096];
    int t = threadIdx.x;
    int base = blockIdx.x * 4096;
    int lim = min(4096, E - base);
    for (int i = t; i < nb; i += 256) hist[i] = 0;
    __syncthreads();
    for (int k = t; k < lim; k += 256) atomicAdd(&hist[dst[base + k] >> 8], 1);
    __syncthreads();
    int v0 = (2 * t < nb) ? hist[2 * t] : 0;
    int v1 = (2 * t + 1 < nb) ? hist[2 * t + 1] : 0;
    int s = v0 + v1;
    ps[t] = s;
    __syncthreads();
    for (int off = 1; off < 256; off <<= 1) {
        int v = (t >= off) ? ps[t - off] : 0;
        __syncthreads();
        ps[t] += v;
        __syncthreads();
    }
    int ex = ps[t] - s;
    if (2 * t < nb) {
        lstart[2 * t] = ex; cur[2 * t] = ex;
        if (v0) gbase[2 * t] = atomicAdd(&gcur[2 * t], v0);
    }
    if (2 * t + 1 < nb) {
        lstart[2 * t + 1] = ex + v0; cur[2 * t + 1] = ex + v0;
        if (v1) gbase[2 * t + 1] = atomicAdd(&gcur[2 * t + 1], v1);
    }
    __syncthreads();
    for (int k = t; k < lim; k += 256) {
        int s_ = src[base + k], d_ = dst[base + k];
        int b = d_ >> 8;
        int slot = atomicAdd(&cur[b], 1);
        stg[slot] = make_uint2((uint)s_, (uint)d_);
        sb[slot] = (ushort)b;
    }
    __syncthreads();
    for (int j = t; j < lim; j += 256) {
        int b = sb[j];
        ebuf[gbase[b] + (j - lstart[b])] = stg[j];
    }
}

__global__ __launch_bounds__(256) void k_rowbuild(const uint2* __restrict__ ebuf,
                                                  const int* __restrict__ boff,
                                                  int* __restrict__ rowptr,
                                                  float* __restrict__ dis,
                                                  int* __restrict__ csr_col,
                                                  int Nn, int nb) {
    int b = blockIdx.x;
    int t = threadIdx.x;
    int beg = boff[b], end = boff[b + 1];
    __shared__ int rcnt[256];
    __shared__ int rstart[256];
    __shared__ int ps[256];
    rcnt[t] = 0;
    __syncthreads();
    for (int e = beg + t; e < end; e += 256)
        atomicAdd(&rcnt[ebuf[e].y & 255], 1);
    __syncthreads();
    int v = rcnt[t];
    ps[t] = v;
    __syncthreads();
    for (int off = 1; off < 256; off <<= 1) {
        int u = (t >= off) ? ps[t - off] : 0;
        __syncthreads();
        ps[t] += u;
        __syncthreads();
    }
    int ex = ps[t] - v;
    int node = b * 256 + t;
    if (node < Nn) {
        rowptr[node] = beg + ex;
        dis[node] = rsqrtf((float)(v + 1));
    }
    rstart[t] = beg + ex;
    __syncthreads();
    rcnt[t] = 0;
    __syncthreads();
    for (int e = beg + t; e < end; e += 256) {
        uint2 ed = ebuf[e];
        int r = ed.y & 255;
        int slot = atomicAdd(&rcnt[r], 1);
        csr_col[rstart[r] + slot] = (int)ed.x;
    }
}

__global__ void k_val(const int* __restrict__ col, const float* __restrict__ dis,
                      float* __restrict__ val, int E) {
    int i = blockIdx.x * 256 + threadIdx.x;
    if (i < E) val[i] = dis[col[i]];
}

// ---------------------------------------------------------------------------
// weight chain helpers
// T = W1 @ Wi  (blocks 0..255) ; S = Wi @ Wi  (blocks 256..511)
// ---------------------------------------------------------------------------
__global__ __launch_bounds__(256) void k_mmTS(const float* __restrict__ W1,
                                              const float* __restrict__ Wi,
                                              float* __restrict__ T,
                                              float* __restrict__ S) {
    int b = blockIdx.x, j = threadIdx.x;
    if (b < 256) {
        float acc = 0.f;
        for (int k = 0; k < 256; ++k) acc = fmaf(W1[b * 256 + k], Wi[k * 256 + j], acc);
        T[b * 256 + j] = acc;
    } else {
        int i = b - 256;
        float acc = 0.f;
        for (int k = 0; k < 256; ++k) acc = fmaf(Wi[i * 256 + k], Wi[k * 256 + j], acc);
        S[i * 256 + j] = acc;
    }
}

// block b computes rows 2b,2b+1 of Wc = T@S and packs them directly into the
// MFMA B-fragment buffer (same fmaf order + pack2 as the old mm256+pack pair).
__global__ __launch_bounds__(256) void k_mm256pack(const float* __restrict__ T,
                                                   const float* __restrict__ S,
                                                   uint* __restrict__ Wp) {
    int b = blockIdx.x, j = threadIdx.x;
    int k0 = 2 * b;
    float r0 = 0.f, r1 = 0.f;
    for (int k = 0; k < 256; ++k) {
        float s = S[k * 256 + j];
        r0 = fmaf(T[k0 * 256 + k], s, r0);
        r1 = fmaf(T[(k0 + 1) * 256 + k], s, r1);
    }
    int kstep = k0 >> 5;
    int lane = ((k0 >> 3) & 3) * 16 + (j & 15);
    int w = (k0 & 7) >> 1;
    int n16 = j >> 4;
    Wp[((n16 * 8 + kstep) * 64 + lane) * 4 + w] = pack2(r0, r1);
}

// all 5 bias-vector chain steps in one block
__global__ __launch_bounds__(256) void k_vchain(const float* __restrict__ b1,
                                                const float* __restrict__ bi,
                                                const float* __restrict__ Wi,
                                                float* __restrict__ c1,
                                                float* __restrict__ c2,
                                                float* __restrict__ c3) {
    __shared__ float v[256];
    int t = threadIdx.x;
    float r;
    v[t] = b1[t]; __syncthreads();
    r = 0.f; for (int k = 0; k < 256; ++k) r = fmaf(v[k], Wi[(size_t)k * 256 + t], r);
    __syncthreads(); v[t] = r; __syncthreads();
    r = 0.f; for (int k = 0; k < 256; ++k) r = fmaf(v[k], Wi[(size_t)k * 256 + t], r);
    __syncthreads(); v[t] = r; __syncthreads();
    r = 0.f; for (int k = 0; k < 256; ++k) r = fmaf(v[k], Wi[(size_t)k * 256 + t], r);
    c1[t] = r;
    __syncthreads(); v[t] = bi[t]; __syncthreads();
    r = 0.f; for (int k = 0; k < 256; ++k) r = fmaf(v[k], Wi[(size_t)k * 256 + t], r);
    c3[t] = r;
    __syncthreads(); v[t] = r; __syncthreads();
    r = 0.f; for (int k = 0; k < 256; ++k) r = fmaf(v[k], Wi[(size_t)k * 256 + t], r);
    c2[t] = r;
}

// ---------------------------------------------------------------------------
// MFMA GEMM: C[M,256](bf16) = x[M,256](fp32, cvt on the fly) @ Wp(bf16 frags)
// block = 32 rows x 256 cols as 4 waves (2 row-groups x 2 col-halves), acc[8]
// ---------------------------------------------------------------------------
__global__ __launch_bounds__(256) void gemm_mfma(const float* __restrict__ A,
                                                 const uint* __restrict__ Wp,
                                                 ushort* __restrict__ C, int M) {
    int t = threadIdx.x;
    int wv = t >> 6;
    int l = t & 63;
    int wr = wv >> 1, wc = wv & 1;
    int m16 = l & 15;
    int kc = l >> 4;
    int bm = blockIdx.x * 32 + wr * 16;
    int n16b = wc * 8;
    int row = bm + m16;
    bool valid = row < M;
    const float* ap = A + (size_t)(valid ? row : 0) * 256 + kc * 8;
    const short8* wp = (const short8*)Wp;

    f32x4 acc[8];
#pragma unroll
    for (int n = 0; n < 8; ++n) acc[n] = {0.f, 0.f, 0.f, 0.f};

#pragma unroll
    for (int ks = 0; ks < 8; ++ks) {
        float4 fa0 = make_float4(0.f, 0.f, 0.f, 0.f), fa1 = fa0;
        if (valid) {
            fa0 = *(const float4*)(ap + ks * 32);
            fa1 = *(const float4*)(ap + ks * 32 + 4);
        }
        short8 a;
        a[0] = (short)f2bf(fa0.x); a[1] = (short)f2bf(fa0.y);
        a[2] = (short)f2bf(fa0.z); a[3] = (short)f2bf(fa0.w);
        a[4] = (short)f2bf(fa1.x); a[5] = (short)f2bf(fa1.y);
        a[6] = (short)f2bf(fa1.z); a[7] = (short)f2bf(fa1.w);
#pragma unroll
        for (int n = 0; n < 8; ++n) {
            short8 b = wp[((n16b + n) * 8 + ks) * 64 + l];
            acc[n] = __builtin_amdgcn_mfma_f32_16x16x32_bf16(a, b, acc[n], 0, 0, 0);
        }
    }

#pragma unroll
    for (int r = 0; r < 4; ++r) {
        int orow = bm + kc * 4 + r;
        if (orow < M) {
            ushort* cp = C + (size_t)orow * 256 + n16b * 16 + m16;
#pragma unroll
            for (int n = 0; n < 8; ++n) cp[n * 16] = f2bf(acc[n][r]);
        }
    }
}

// ---------------------------------------------------------------------------
// Fused bf16 propagation + scalar propagation.
// MODE 1: first pass  — also computes s_out[d] = A_hat·1        (s_in unused)
// MODE 0: middle pass — also computes s_out[d] = A_hat·s_in
// MODE 2: final pass  — rank-1 epilogue from s1,s2,s3 (no s compute)
// 4 waves/block = 4 nodes; lane owns 4 features; 8 edges in flight.
// Scalar s-gathers are wave-uniform broadcast loads (s arrays are L2-resident).
// ---------------------------------------------------------------------------
template <int MODE>
__global__ __launch_bounds__(256) void k_aggb(const uint* __restrict__ y,
                                              const int* __restrict__ rowptr,
                                              const int* __restrict__ col,
                                              const float* __restrict__ val,
                                              const float* __restrict__ dis,
                                              const float* __restrict__ s_in,
                                              float* __restrict__ s_out,
                                              const float* __restrict__ s1,
                                              const float* __restrict__ s2,
                                              const float* __restrict__ s3,
                                              const float* __restrict__ c1,
                                              const float* __restrict__ c2,
                                              const float* __restrict__ c3,
                                              const float* __restrict__ c4,
                                              uint* __restrict__ out, int Nn) {
    int wid = threadIdx.x >> 6;
    int t = threadIdx.x & 63;
    int d = blockIdx.x * 4 + wid;
    if (d >= Nn) return;
    const uint* yt = y + 2 * t;
    int beg = rowptr[d], end = rowptr[d + 1];
    float a0 = 0.f, a1 = 0.f, a2 = 0.f, a3 = 0.f;
    float sv = 0.f;
    int e = beg;
    for (; e + 7 < end; e += 8) {
        int cc[8]; float vv[8]; uint2 uu[8];
#pragma unroll
        for (int j = 0; j < 8; ++j) { cc[j] = col[e + j]; vv[j] = val[e + j]; }
#pragma unroll
        for (int j = 0; j < 8; ++j) uu[j] = *(const uint2*)(yt + (size_t)cc[j] * 128);
#pragma unroll
        for (int j = 0; j < 8; ++j) {
            if (MODE == 1) sv += vv[j];
            if (MODE == 0) sv = fmaf(vv[j], s_in[cc[j]], sv);
            a0 = fmaf(vv[j], blo(uu[j].x), a0);
            a1 = fmaf(vv[j], bhi(uu[j].x), a1);
            a2 = fmaf(vv[j], blo(uu[j].y), a2);
            a3 = fmaf(vv[j], bhi(uu[j].y), a3);
        }
    }
    if (e + 3 < end) {
        int cc[4]; float vv[4]; uint2 uu[4];
#pragma unroll
        for (int j = 0; j < 4; ++j) { cc[j] = col[e + j]; vv[j] = val[e + j]; }
#pragma unroll
        for (int j = 0; j < 4; ++j) uu[j] = *(const uint2*)(yt + (size_t)cc[j] * 128);
#pragma unroll
        for (int j = 0; j < 4; ++j) {
            if (MODE == 1) sv += vv[j];
            if (MODE == 0) sv = fmaf(vv[j], s_in[cc[j]], sv);
            a0 = fmaf(vv[j], blo(uu[j].x), a0);
            a1 = fmaf(vv[j], bhi(uu[j].x), a1);
            a2 = fmaf(vv[j], blo(uu[j].y), a2);
            a3 = fmaf(vv[j], bhi(uu[j].y), a3);
        }
        e += 4;
    }
    for (; e < end; ++e) {
        int c = col[e]; float v = val[e];
        uint2 u = *(const uint2*)(yt + (size_t)c * 128);
        if (MODE == 1) sv += v;
        if (MODE == 0) sv = fmaf(v, s_in[c], sv);
        a0 = fmaf(v, blo(u.x), a0); a1 = fmaf(v, bhi(u.x), a1);
        a2 = fmaf(v, blo(u.y), a2); a3 = fmaf(v, bhi(u.y), a3);
    }
    float dd = dis[d];
    float d2 = dd * dd;
    if (MODE == 1 && t == 0) s_out[d] = fmaf(dd, sv, d2 * 1.f);
    if (MODE == 0 && t == 0) s_out[d] = fmaf(dd, sv, d2 * s_in[d]);
    uint2 us = *(const uint2*)(yt + (size_t)d * 128);
    float r0 = fmaf(dd, a0, d2 * blo(us.x));
    float r1 = fmaf(dd, a1, d2 * bhi(us.x));
    float r2 = fmaf(dd, a2, d2 * blo(us.y));
    float r3 = fmaf(dd, a3, d2 * bhi(us.y));
    if (MODE == 2) {
        float4 C1 = *(const float4*)(c1 + 4 * t);
        float4 C2 = *(const float4*)(c2 + 4 * t);
        float4 C3 = *(const float4*)(c3 + 4 * t);
        float4 C4 = *(const float4*)(c4 + 4 * t);
        float S1 = s1[d], S2 = s2[d], S3 = s3[d];
        r0 += S3 * C1.x + S2 * C2.x + S1 * C3.x + C4.x;
        r1 += S3 * C1.y + S2 * C2.y + S1 * C3.y + C4.y;
        r2 += S3 * C1.z + S2 * C2.z + S1 * C3.z + C4.z;
        r3 += S3 * C1.w + S2 * C2.w + S1 * C3.w + C4.w;
    }
    uint2 o;
    o.x = pack2(r0, r1);
    o.y = pack2(r2, r3);
    *(uint2*)(out + (size_t)d * 128 + 2 * t) = o;
}

// ---------------------------------------------------------------------------
// final layer: Y[M,16](f32) = relu(A[M,256](bf16)) @ W2[256,16](f32)
// ---------------------------------------------------------------------------
__global__ __launch_bounds__(256) void k_gemm16b(const uint* __restrict__ A,
                                                 const float* __restrict__ W2,
                                                 float* __restrict__ Y, int M) {
    __shared__ float Ws[256][16];
    int t = threadIdx.x;
    for (int i = t; i < 256 * 16; i += 256) Ws[i >> 4][i & 15] = W2[i];
    __syncthreads();
    int tx = t & 15, ty = t >> 4;
    int r = blockIdx.x * 16 + ty;
    if (r >= M) return;
    const uint* a = A + (size_t)r * 128;
    float acc = 0.f;
    for (int i = 0; i < 128; i += 4) {
        uint4 u = *(const uint4*)(a + i);
        float f;
        f = fmaxf(blo(u.x), 0.f); acc = fmaf(f, Ws[2 * i + 0][tx], acc);
        f = fmaxf(bhi(u.x), 0.f); acc = fmaf(f, Ws[2 * i + 1][tx], acc);
        f = fmaxf(blo(u.y), 0.f); acc = fmaf(f, Ws[2 * i + 2][tx], acc);
        f = fmaxf(bhi(u.y), 0.f); acc = fmaf(f, Ws[2 * i + 3][tx], acc);
        f = fmaxf(blo(u.z), 0.f); acc = fmaf(f, Ws[2 * i + 4][tx], acc);
        f = fmaxf(bhi(u.z), 0.f); acc = fmaf(f, Ws[2 * i + 5][tx], acc);
        f = fmaxf(blo(u.w), 0.f); acc = fmaf(f, Ws[2 * i + 6][tx], acc);
        f = fmaxf(bhi(u.w), 0.f); acc = fmaf(f, Ws[2 * i + 7][tx], acc);
    }
    Y[(size_t)r * NCLS + tx] = acc;
}

// propagation at width 16 (fp32)
__global__ __launch_bounds__(256) void k_agg16(const float* __restrict__ y16,
                                               const int* __restrict__ rowptr,
                                               const int* __restrict__ col,
                                               const float* __restrict__ val,
                                               const float* __restrict__ dis,
                                               const float* __restrict__ b2,
                                               float* __restrict__ out, int Nn) {
    int t = threadIdx.x;
    int tx = t & 15, ty = t >> 4;
    int d = blockIdx.x * 16 + ty;
    if (d >= Nn) return;
    int beg = rowptr[d], end = rowptr[d + 1];
    float acc = 0.f;
    for (int e = beg; e < end; ++e)
        acc = fmaf(val[e], y16[(size_t)col[e] * NCLS + tx], acc);
    float dd = dis[d];
    out[(size_t)d * NCLS + tx] = dd * acc + dd * dd * y16[(size_t)d * NCLS + tx] + b2[tx];
}

// ---------------------------------------------------------------------------
// softmax over axis 0
// ---------------------------------------------------------------------------
__global__ __launch_bounds__(256) void k_sm1(const float* __restrict__ z,
                                             float* __restrict__ pmax,
                                             float* __restrict__ psum, int Nn) {
    int b = blockIdx.x, t = threadIdx.x, tx = t & 15, ty = t >> 4;
    int CH = (Nn + 255) / 256;
    int r0 = b * CH, r1 = min(r0 + CH, Nn);
    __shared__ float red[16][17];
    __shared__ float gloc[16];
    float m = -3.4e38f;
    for (int r = r0 + ty; r < r1; r += 16) m = fmaxf(m, z[(size_t)r * NCLS + tx]);
    red[ty][tx] = m;
    __syncthreads();
    if (ty == 0) {
        float mm = red[0][tx];
#pragma unroll
        for (int i = 1; i < 16; ++i) mm = fmaxf(mm, red[i][tx]);
        gloc[tx] = mm;
    }
    __syncthreads();
    float g = gloc[tx];
    float s = 0.f;
    for (int r = r0 + ty; r < r1; r += 16) s += expf(z[(size_t)r * NCLS + tx] - g);
    red[ty][tx] = s;
    __syncthreads();
    if (ty == 0) {
        float ss = red[0][tx];
#pragma unroll
        for (int i = 1; i < 16; ++i) ss += red[i][tx];
        pmax[b * 16 + tx] = g;
        psum[b * 16 + tx] = ss;
    }
}

__global__ __launch_bounds__(256) void k_sm2(const float* __restrict__ pmax,
                                             const float* __restrict__ psum,
                                             float* __restrict__ g16,
                                             float* __restrict__ inv16) {
    int t = threadIdx.x, tx = t & 15, ty = t >> 4;
    __shared__ float red[16][17];
    __shared__ float gsh[16];
    float m = -3.4e38f;
    for (int b = ty; b < 256; b += 16) m = fmaxf(m, pmax[b * 16 + tx]);
    red[ty][tx] = m;
    __syncthreads();
    if (ty == 0) {
        float mm = red[0][tx];
#pragma unroll
        for (int i = 1; i < 16; ++i) mm = fmaxf(mm, red[i][tx]);
        gsh[tx] = mm;
    }
    __syncthreads();
    float g = gsh[tx];
    float s = 0.f;
    for (int b = ty; b < 256; b += 16)
        s += psum[b * 16 + tx] * expf(pmax[b * 16 + tx] - g);
    red[ty][tx] = s;
    __syncthreads();
    if (ty == 0) {
        float ss = red[0][tx];
#pragma unroll
        for (int i = 1; i < 16; ++i) ss += red[i][tx];
        g16[tx] = g;
        inv16[tx] = 1.0f / ss;
    }
}

__global__ void k_sm5(float* __restrict__ z, const float* __restrict__ g16,
                      const float* __restrict__ inv16, int total) {
    int i = blockIdx.x * 256 + threadIdx.x;
    if (i < total) {
        int c = i & 15;
        z[i] = expf(z[i] - g16[c]) * inv16[c];
    }
}

// ---------------------------------------------------------------------------
extern "C" void kernel_launch(void* const* d_in, const int* in_sizes, int n_in,
                              void* d_out, int out_size, void* d_ws, size_t ws_size,
                              hipStream_t stream) {
    const float* x  = (const float*)d_in[0];
    const int*   ei = (const int*)d_in[1];
    const float* W1 = (const float*)d_in[2];
    const float* b1 = (const float*)d_in[3];
    const float* Wi = (const float*)d_in[4];
    const float* bi = (const float*)d_in[5];
    const float* W2 = (const float*)d_in[6];
    const float* b2 = (const float*)d_in[7];
    float* out = (float*)d_out;

    int Nn = in_sizes[0] / NFEAT;   // 100000
    int E  = in_sizes[1] / 2;       // 1600000
    int nb = (Nn + 255) >> 8;       // 391 coarse buckets
    const int* esrc = ei;
    const int* edst = ei + E;

    char* p = (char*)d_ws;
    auto carve = [&](size_t bytes) -> char* {
        char* r = p;
        p += (bytes + 255) / 256 * 256;
        return r;
    };
    uint*  bufA    = (uint*) carve((size_t)Nn * 128 * 4);   // bf16 features
    uint*  bufB    = (uint*) carve((size_t)Nn * 128 * 4);
    int*   rowptr  = (int*)  carve((size_t)(Nn + 1) * 4);
    float* dis     = (float*)carve((size_t)Nn * 4);
    int*   csr_col = (int*)  carve((size_t)E * 4);
    float* csr_val = (float*)carve((size_t)E * 4);
    uint2* ebuf    = (uint2*)carve((size_t)E * 8);
    int*   bhist   = (int*)  carve(512 * 4);
    int*   boff    = (int*)  carve(512 * 4);
    int*   gcur    = (int*)  carve(512 * 4);
    float* y16     = (float*)carve((size_t)Nn * NCLS * 4);
    float* s1      = (float*)carve((size_t)Nn * 4);
    float* s2      = (float*)carve((size_t)Nn * 4);
    float* s3      = (float*)carve((size_t)Nn * 4);
    float* WA      = (float*)carve(256 * 256 * 4);   // T = W1 Wi
    float* WB      = (float*)carve(256 * 256 * 4);   // S = Wi Wi
    uint*  Wp      = (uint*) carve(32768 * 4);
    float* c1      = (float*)carve(256 * 4);
    float* c2      = (float*)carve(256 * 4);
    float* c3      = (float*)carve(256 * 4);
    float* pmax    = (float*)carve(256 * 16 * 4);
    float* psum    = (float*)carve(256 * 16 * 4);
    float* g16     = (float*)carve(16 * 4);
    float* inv16   = (float*)carve(16 * 4);

    hipMemsetAsync(bhist, 0, 512 * 4, stream);

    int gE = (E + 255) / 256;
    int nch = (E + 4095) / 4096;

    // graph build (bucketed counting sort)
    k_ccount<<<1024, 256, 0, stream>>>(edst, bhist, E, nb);
    k_cscan<<<1, 256, 0, stream>>>(bhist, boff, gcur, rowptr, nb, Nn);
    k_cfill<<<nch, 256, 0, stream>>>(esrc, edst, gcur, ebuf, E, nb);
    k_rowbuild<<<nb, 256, 0, stream>>>(ebuf, boff, rowptr, dis, csr_col, Nn, nb);
    k_val<<<gE, 256, 0, stream>>>(csr_col, dis, csr_val, E);

    // weight chain: {T, S} ; Wp = pack(T S) ; bias vectors
    k_mmTS<<<512, 256, 0, stream>>>(W1, Wi, WA, WB);
    k_mm256pack<<<128, 256, 0, stream>>>(WA, WB, Wp);
    k_vchain<<<1, 256, 0, stream>>>(b1, bi, Wi, c1, c2, c3);

    // y0 = x @ Wc  (fp32 in, bf16 out, MFMA; A read once)
    gemm_mfma<<<(Nn + 31) / 32, 256, 0, stream>>>(x, Wp, (ushort*)bufB, Nn);

    // h4 = A^4 y0 + rank-1 terms; scalar vectors s1,s2,s3 fused into passes 1-3
    int gA = (Nn + 3) / 4;
    k_aggb<1><<<gA, 256, 0, stream>>>(bufB, rowptr, csr_col, csr_val, dis,
                                      nullptr, s1, nullptr, nullptr, nullptr,
                                      nullptr, nullptr, nullptr, nullptr, bufA, Nn);
    k_aggb<0><<<gA, 256, 0, stream>>>(bufA, rowptr, csr_col, csr_val, dis,
                                      s1, s2, nullptr, nullptr, nullptr,
                                      nullptr, nullptr, nullptr, nullptr, bufB, Nn);
    k_aggb<0><<<gA, 256, 0, stream>>>(bufB, rowptr, csr_col, csr_val, dis,
                                      s2, s3, nullptr, nullptr, nullptr,
                                      nullptr, nullptr, nullptr, nullptr, bufA, Nn);
    k_aggb<2><<<gA, 256, 0, stream>>>(bufA, rowptr, csr_col, csr_val, dis,
                                      nullptr, nullptr, s1, s2, s3,
                                      c1, c2, c3, bi, bufB, Nn);

    // final: z = A(relu(h4) W2) + b2 ; softmax over nodes
    int g16b = (Nn + 15) / 16;
    k_gemm16b<<<g16b, 256, 0, stream>>>(bufB, W2, y16, Nn);
    k_agg16<<<g16b, 256, 0, stream>>>(y16, rowptr, csr_col, csr_val, dis, b2, out, Nn);

    k_sm1<<<256, 256, 0, stream>>>(out, pmax, psum, Nn);
    k_sm2<<<1, 256, 0, stream>>>(pmax, psum, g16, inv16);
    k_sm5<<<(Nn * NCLS + 255) / 256, 256, 0, stream>>>(out, g16, inv16, Nn * NCLS);
}

// Round 10
// 800.337 us; speedup vs baseline: 1.1478x; 1.0272x over previous
//
#include <hip/hip_runtime.h>
#include <cstdint>
#include <cstddef>

#define NFEAT 256
#define NCLS  16

typedef unsigned int uint;
typedef unsigned short ushort;
typedef __attribute__((ext_vector_type(8))) short short8;
typedef __attribute__((ext_vector_type(4))) float f32x4;

__device__ inline float blo(uint u) { return __uint_as_float(u << 16); }
__device__ inline float bhi(uint u) { return __uint_as_float(u & 0xffff0000u); }
__device__ inline ushort f2bf(float f) {
    uint b = __float_as_uint(f);
    b += 0x7fffu + ((b >> 16) & 1u);
    return (ushort)(b >> 16);
}
__device__ inline uint pack2(float a, float b) {
    return (uint)f2bf(a) | ((uint)f2bf(b) << 16);
}

// ---------------------------------------------------------------------------
// Graph build: bucketed counting sort (bucket = dst >> 8, 391 buckets)
// ---------------------------------------------------------------------------
__global__ __launch_bounds__(256) void k_ccount(const int* __restrict__ dst,
                                                int* __restrict__ bhist, int E, int nb) {
    __shared__ int h[512];
    int t = threadIdx.x;
    for (int i = t; i < nb; i += 256) h[i] = 0;
    __syncthreads();
    for (int i = blockIdx.x * 256 + t; i < E; i += gridDim.x * 256)
        atomicAdd(&h[dst[i] >> 8], 1);
    __syncthreads();
    for (int i = t; i < nb; i += 256)
        if (h[i]) atomicAdd(&bhist[i], h[i]);
}

__global__ __launch_bounds__(256) void k_cscan(const int* __restrict__ bhist,
                                               int* __restrict__ boff,
                                               int* __restrict__ gcur,
                                               int* __restrict__ rowptr,
                                               int nb, int Nn) {
    int t = threadIdx.x;
    int v0 = (2 * t < nb) ? bhist[2 * t] : 0;
    int v1 = (2 * t + 1 < nb) ? bhist[2 * t + 1] : 0;
    int s = v0 + v1;
    __shared__ int ps[256];
    ps[t] = s;
    __syncthreads();
    for (int off = 1; off < 256; off <<= 1) {
        int v = (t >= off) ? ps[t - off] : 0;
        __syncthreads();
        ps[t] += v;
        __syncthreads();
    }
    int ex = ps[t] - s;
    if (2 * t < nb)     { boff[2 * t] = ex;          gcur[2 * t] = ex; }
    if (2 * t + 1 < nb) { boff[2 * t + 1] = ex + v0; gcur[2 * t + 1] = ex + v0; }
    if (t == 255) { boff[nb] = ps[255]; rowptr[Nn] = ps[255]; }
}

__global__ __launch_bounds__(256) void k_cfill(const int* __restrict__ src,
                                               const int* __restrict__ dst,
                                               int* __restrict__ gcur,
                                               uint2* __restrict__ ebuf, int E, int nb) {
    __shared__ int hist[400];
    __shared__ int lstart[400];
    __shared__ int gbase[400];
    __shared__ int cur[400];
    __shared__ int ps[256];
    __shared__ uint2 stg[4096];
    __shared__ ushort sb[4096];
    int t = threadIdx.x;
    int base = blockIdx.x * 4096;
    int lim = min(4096, E - base);
    for (int i = t; i < nb; i += 256) hist[i] = 0;
    __syncthreads();
    for (int k = t; k < lim; k += 256) atomicAdd(&hist[dst[base + k] >> 8], 1);
    __syncthreads();
    int v0 = (2 * t < nb) ? hist[2 * t] : 0;
    int v1 = (2 * t + 1 < nb) ? hist[2 * t + 1] : 0;
    int s = v0 + v1;
    ps[t] = s;
    __syncthreads();
    for (int off = 1; off < 256; off <<= 1) {
        int v = (t >= off) ? ps[t - off] : 0;
        __syncthreads();
        ps[t] += v;
        __syncthreads();
    }
    int ex = ps[t] - s;
    if (2 * t < nb) {
        lstart[2 * t] = ex; cur[2 * t] = ex;
        if (v0) gbase[2 * t] = atomicAdd(&gcur[2 * t], v0);
    }
    if (2 * t + 1 < nb) {
        lstart[2 * t + 1] = ex + v0; cur[2 * t + 1] = ex + v0;
        if (v1) gbase[2 * t + 1] = atomicAdd(&gcur[2 * t + 1], v1);
    }
    __syncthreads();
    for (int k = t; k < lim; k += 256) {
        int s_ = src[base + k], d_ = dst[base + k];
        int b = d_ >> 8;
        int slot = atomicAdd(&cur[b], 1);
        stg[slot] = make_uint2((uint)s_, (uint)d_);
        sb[slot] = (ushort)b;
    }
    __syncthreads();
    for (int j = t; j < lim; j += 256) {
        int b = sb[j];
        ebuf[gbase[b] + (j - lstart[b])] = stg[j];
    }
}

__global__ __launch_bounds__(256) void k_rowbuild(const uint2* __restrict__ ebuf,
                                                  const int* __restrict__ boff,
                                                  int* __restrict__ rowptr,
                                                  float* __restrict__ dis,
                                                  int* __restrict__ csr_col,
                                                  int Nn, int nb) {
    int b = blockIdx.x;
    int t = threadIdx.x;
    int beg = boff[b], end = boff[b + 1];
    __shared__ int rcnt[256];
    __shared__ int rstart[256];
    __shared__ int ps[256];
    rcnt[t] = 0;
    __syncthreads();
    for (int e = beg + t; e < end; e += 256)
        atomicAdd(&rcnt[ebuf[e].y & 255], 1);
    __syncthreads();
    int v = rcnt[t];
    ps[t] = v;
    __syncthreads();
    for (int off = 1; off < 256; off <<= 1) {
        int u = (t >= off) ? ps[t - off] : 0;
        __syncthreads();
        ps[t] += u;
        __syncthreads();
    }
    int ex = ps[t] - v;
    int node = b * 256 + t;
    if (node < Nn) {
        rowptr[node] = beg + ex;
        dis[node] = rsqrtf((float)(v + 1));
    }
    rstart[t] = beg + ex;
    __syncthreads();
    rcnt[t] = 0;
    __syncthreads();
    for (int e = beg + t; e < end; e += 256) {
        uint2 ed = ebuf[e];
        int r = ed.y & 255;
        int slot = atomicAdd(&rcnt[r], 1);
        csr_col[rstart[r] + slot] = (int)ed.x;
    }
}

__global__ void k_val(const int* __restrict__ col, const float* __restrict__ dis,
                      float* __restrict__ val, int E) {
    int i = blockIdx.x * 256 + threadIdx.x;
    if (i < E) val[i] = dis[col[i]];
}

// ---------------------------------------------------------------------------
// weight chain helpers
// T = W1 @ Wi  (blocks 0..255) ; S = Wi @ Wi  (blocks 256..511)
// ---------------------------------------------------------------------------
__global__ __launch_bounds__(256) void k_mmTS(const float* __restrict__ W1,
                                              const float* __restrict__ Wi,
                                              float* __restrict__ T,
                                              float* __restrict__ S) {
    int b = blockIdx.x, j = threadIdx.x;
    if (b < 256) {
        float acc = 0.f;
        for (int k = 0; k < 256; ++k) acc = fmaf(W1[b * 256 + k], Wi[k * 256 + j], acc);
        T[b * 256 + j] = acc;
    } else {
        int i = b - 256;
        float acc = 0.f;
        for (int k = 0; k < 256; ++k) acc = fmaf(Wi[i * 256 + k], Wi[k * 256 + j], acc);
        S[i * 256 + j] = acc;
    }
}

// block b computes rows 2b,2b+1 of Wc = T@S and packs them directly into the
// MFMA B-fragment buffer.
__global__ __launch_bounds__(256) void k_mm256pack(const float* __restrict__ T,
                                                   const float* __restrict__ S,
                                                   uint* __restrict__ Wp) {
    int b = blockIdx.x, j = threadIdx.x;
    int k0 = 2 * b;
    float r0 = 0.f, r1 = 0.f;
    for (int k = 0; k < 256; ++k) {
        float s = S[k * 256 + j];
        r0 = fmaf(T[k0 * 256 + k], s, r0);
        r1 = fmaf(T[(k0 + 1) * 256 + k], s, r1);
    }
    int kstep = k0 >> 5;
    int lane = ((k0 >> 3) & 3) * 16 + (j & 15);
    int w = (k0 & 7) >> 1;
    int n16 = j >> 4;
    Wp[((n16 * 8 + kstep) * 64 + lane) * 4 + w] = pack2(r0, r1);
}

// bias-vector chain: c1 = b1 Wi^3, c2 = bi Wi^2, c3 = bi Wi  (one block)
__global__ __launch_bounds__(256) void k_vchain(const float* __restrict__ b1,
                                                const float* __restrict__ bi,
                                                const float* __restrict__ Wi,
                                                float* __restrict__ c1,
                                                float* __restrict__ c2,
                                                float* __restrict__ c3) {
    __shared__ float v[256];
    int t = threadIdx.x;
    float r;
    v[t] = b1[t]; __syncthreads();
    r = 0.f; for (int k = 0; k < 256; ++k) r = fmaf(v[k], Wi[(size_t)k * 256 + t], r);
    __syncthreads(); v[t] = r; __syncthreads();
    r = 0.f; for (int k = 0; k < 256; ++k) r = fmaf(v[k], Wi[(size_t)k * 256 + t], r);
    __syncthreads(); v[t] = r; __syncthreads();
    r = 0.f; for (int k = 0; k < 256; ++k) r = fmaf(v[k], Wi[(size_t)k * 256 + t], r);
    c1[t] = r;
    __syncthreads(); v[t] = bi[t]; __syncthreads();
    r = 0.f; for (int k = 0; k < 256; ++k) r = fmaf(v[k], Wi[(size_t)k * 256 + t], r);
    c3[t] = r;
    __syncthreads(); v[t] = r; __syncthreads();
    r = 0.f; for (int k = 0; k < 256; ++k) r = fmaf(v[k], Wi[(size_t)k * 256 + t], r);
    c2[t] = r;
}

// ---------------------------------------------------------------------------
// MFMA GEMM: C[M,256](bf16) = x[M,256](fp32, cvt on the fly) @ Wp(bf16 frags)
// block = 32 rows x 256 cols as 4 waves (2 row-groups x 2 col-halves), acc[8]
// ---------------------------------------------------------------------------
__global__ __launch_bounds__(256) void gemm_mfma(const float* __restrict__ A,
                                                 const uint* __restrict__ Wp,
                                                 ushort* __restrict__ C, int M) {
    int t = threadIdx.x;
    int wv = t >> 6;
    int l = t & 63;
    int wr = wv >> 1, wc = wv & 1;
    int m16 = l & 15;
    int kc = l >> 4;
    int bm = blockIdx.x * 32 + wr * 16;
    int n16b = wc * 8;
    int row = bm + m16;
    bool valid = row < M;
    const float* ap = A + (size_t)(valid ? row : 0) * 256 + kc * 8;
    const short8* wp = (const short8*)Wp;

    f32x4 acc[8];
#pragma unroll
    for (int n = 0; n < 8; ++n) acc[n] = {0.f, 0.f, 0.f, 0.f};

#pragma unroll
    for (int ks = 0; ks < 8; ++ks) {
        float4 fa0 = make_float4(0.f, 0.f, 0.f, 0.f), fa1 = fa0;
        if (valid) {
            fa0 = *(const float4*)(ap + ks * 32);
            fa1 = *(const float4*)(ap + ks * 32 + 4);
        }
        short8 a;
        a[0] = (short)f2bf(fa0.x); a[1] = (short)f2bf(fa0.y);
        a[2] = (short)f2bf(fa0.z); a[3] = (short)f2bf(fa0.w);
        a[4] = (short)f2bf(fa1.x); a[5] = (short)f2bf(fa1.y);
        a[6] = (short)f2bf(fa1.z); a[7] = (short)f2bf(fa1.w);
#pragma unroll
        for (int n = 0; n < 8; ++n) {
            short8 b = wp[((n16b + n) * 8 + ks) * 64 + l];
            acc[n] = __builtin_amdgcn_mfma_f32_16x16x32_bf16(a, b, acc[n], 0, 0, 0);
        }
    }

#pragma unroll
    for (int r = 0; r < 4; ++r) {
        int orow = bm + kc * 4 + r;
        if (orow < M) {
            ushort* cp = C + (size_t)orow * 256 + n16b * 16 + m16;
#pragma unroll
            for (int n = 0; n < 8; ++n) cp[n * 16] = f2bf(acc[n][r]);
        }
    }
}

// ---------------------------------------------------------------------------
// bf16 propagation + per-feature bias:
//   out[d] = bf16( dis_d*sum(val*y[col]) + dis_d^2*y[d] + cvec[feature] )
// 4 waves/block = 4 nodes; lane owns 4 features (uint2); 8 edges in flight.
// [round-8 loop body — pinned at pattern BW ceiling; bias = 1 float4/lane]
// ---------------------------------------------------------------------------
__global__ __launch_bounds__(256) void k_aggb(const uint* __restrict__ y,
                                              const int* __restrict__ rowptr,
                                              const int* __restrict__ col,
                                              const float* __restrict__ val,
                                              const float* __restrict__ dis,
                                              const float* __restrict__ cvec,
                                              uint* __restrict__ out, int Nn) {
    int wid = threadIdx.x >> 6;
    int t = threadIdx.x & 63;
    int d = blockIdx.x * 4 + wid;
    if (d >= Nn) return;
    const uint* yt = y + 2 * t;
    int beg = rowptr[d], end = rowptr[d + 1];
    float a0 = 0.f, a1 = 0.f, a2 = 0.f, a3 = 0.f;
    int e = beg;
    for (; e + 7 < end; e += 8) {
        int cc[8]; float vv[8]; uint2 uu[8];
#pragma unroll
        for (int j = 0; j < 8; ++j) { cc[j] = col[e + j]; vv[j] = val[e + j]; }
#pragma unroll
        for (int j = 0; j < 8; ++j) uu[j] = *(const uint2*)(yt + (size_t)cc[j] * 128);
#pragma unroll
        for (int j = 0; j < 8; ++j) {
            a0 = fmaf(vv[j], blo(uu[j].x), a0);
            a1 = fmaf(vv[j], bhi(uu[j].x), a1);
            a2 = fmaf(vv[j], blo(uu[j].y), a2);
            a3 = fmaf(vv[j], bhi(uu[j].y), a3);
        }
    }
    if (e + 3 < end) {
        int cc[4]; float vv[4]; uint2 uu[4];
#pragma unroll
        for (int j = 0; j < 4; ++j) { cc[j] = col[e + j]; vv[j] = val[e + j]; }
#pragma unroll
        for (int j = 0; j < 4; ++j) uu[j] = *(const uint2*)(yt + (size_t)cc[j] * 128);
#pragma unroll
        for (int j = 0; j < 4; ++j) {
            a0 = fmaf(vv[j], blo(uu[j].x), a0);
            a1 = fmaf(vv[j], bhi(uu[j].x), a1);
            a2 = fmaf(vv[j], blo(uu[j].y), a2);
            a3 = fmaf(vv[j], bhi(uu[j].y), a3);
        }
        e += 4;
    }
    for (; e < end; ++e) {
        int c = col[e]; float v = val[e];
        uint2 u = *(const uint2*)(yt + (size_t)c * 128);
        a0 = fmaf(v, blo(u.x), a0); a1 = fmaf(v, bhi(u.x), a1);
        a2 = fmaf(v, blo(u.y), a2); a3 = fmaf(v, bhi(u.y), a3);
    }
    float dd = dis[d];
    float d2 = dd * dd;
    uint2 us = *(const uint2*)(yt + (size_t)d * 128);
    float4 C = *(const float4*)(cvec + 4 * t);
    float r0 = fmaf(dd, a0, d2 * blo(us.x)) + C.x;
    float r1 = fmaf(dd, a1, d2 * bhi(us.x)) + C.y;
    float r2 = fmaf(dd, a2, d2 * blo(us.y)) + C.z;
    float r3 = fmaf(dd, a3, d2 * bhi(us.y)) + C.w;
    uint2 o;
    o.x = pack2(r0, r1);
    o.y = pack2(r2, r3);
    *(uint2*)(out + (size_t)d * 128 + 2 * t) = o;
}

// ---------------------------------------------------------------------------
// final layer: Y[M,16](f32) = relu(A[M,256](bf16)) @ W2[256,16](f32)
// ---------------------------------------------------------------------------
__global__ __launch_bounds__(256) void k_gemm16b(const uint* __restrict__ A,
                                                 const float* __restrict__ W2,
                                                 float* __restrict__ Y, int M) {
    __shared__ float Ws[256][16];
    int t = threadIdx.x;
    for (int i = t; i < 256 * 16; i += 256) Ws[i >> 4][i & 15] = W2[i];
    __syncthreads();
    int tx = t & 15, ty = t >> 4;
    int r = blockIdx.x * 16 + ty;
    if (r >= M) return;
    const uint* a = A + (size_t)r * 128;
    float acc = 0.f;
    for (int i = 0; i < 128; i += 4) {
        uint4 u = *(const uint4*)(a + i);
        float f;
        f = fmaxf(blo(u.x), 0.f); acc = fmaf(f, Ws[2 * i + 0][tx], acc);
        f = fmaxf(bhi(u.x), 0.f); acc = fmaf(f, Ws[2 * i + 1][tx], acc);
        f = fmaxf(blo(u.y), 0.f); acc = fmaf(f, Ws[2 * i + 2][tx], acc);
        f = fmaxf(bhi(u.y), 0.f); acc = fmaf(f, Ws[2 * i + 3][tx], acc);
        f = fmaxf(blo(u.z), 0.f); acc = fmaf(f, Ws[2 * i + 4][tx], acc);
        f = fmaxf(bhi(u.z), 0.f); acc = fmaf(f, Ws[2 * i + 5][tx], acc);
        f = fmaxf(blo(u.w), 0.f); acc = fmaf(f, Ws[2 * i + 6][tx], acc);
        f = fmaxf(bhi(u.w), 0.f); acc = fmaf(f, Ws[2 * i + 7][tx], acc);
    }
    Y[(size_t)r * NCLS + tx] = acc;
}

// propagation at width 16 (fp32)
__global__ __launch_bounds__(256) void k_agg16(const float* __restrict__ y16,
                                               const int* __restrict__ rowptr,
                                               const int* __restrict__ col,
                                               const float* __restrict__ val,
                                               const float* __restrict__ dis,
                                               const float* __restrict__ b2,
                                               float* __restrict__ out, int Nn) {
    int t = threadIdx.x;
    int tx = t & 15, ty = t >> 4;
    int d = blockIdx.x * 16 + ty;
    if (d >= Nn) return;
    int beg = rowptr[d], end = rowptr[d + 1];
    float acc = 0.f;
    for (int e = beg; e < end; ++e)
        acc = fmaf(val[e], y16[(size_t)col[e] * NCLS + tx], acc);
    float dd = dis[d];
    out[(size_t)d * NCLS + tx] = dd * acc + dd * dd * y16[(size_t)d * NCLS + tx] + b2[tx];
}

// ---------------------------------------------------------------------------
// softmax over axis 0
// ---------------------------------------------------------------------------
__global__ __launch_bounds__(256) void k_sm1(const float* __restrict__ z,
                                             float* __restrict__ pmax,
                                             float* __restrict__ psum, int Nn) {
    int b = blockIdx.x, t = threadIdx.x, tx = t & 15, ty = t >> 4;
    int CH = (Nn + 255) / 256;
    int r0 = b * CH, r1 = min(r0 + CH, Nn);
    __shared__ float red[16][17];
    __shared__ float gloc[16];
    float m = -3.4e38f;
    for (int r = r0 + ty; r < r1; r += 16) m = fmaxf(m, z[(size_t)r * NCLS + tx]);
    red[ty][tx] = m;
    __syncthreads();
    if (ty == 0) {
        float mm = red[0][tx];
#pragma unroll
        for (int i = 1; i < 16; ++i) mm = fmaxf(mm, red[i][tx]);
        gloc[tx] = mm;
    }
    __syncthreads();
    float g = gloc[tx];
    float s = 0.f;
    for (int r = r0 + ty; r < r1; r += 16) s += expf(z[(size_t)r * NCLS + tx] - g);
    red[ty][tx] = s;
    __syncthreads();
    if (ty == 0) {
        float ss = red[0][tx];
#pragma unroll
        for (int i = 1; i < 16; ++i) ss += red[i][tx];
        pmax[b * 16 + tx] = g;
        psum[b * 16 + tx] = ss;
    }
}

__global__ __launch_bounds__(256) void k_sm2(const float* __restrict__ pmax,
                                             const float* __restrict__ psum,
                                             float* __restrict__ g16,
                                             float* __restrict__ inv16) {
    int t = threadIdx.x, tx = t & 15, ty = t >> 4;
    __shared__ float red[16][17];
    __shared__ float gsh[16];
    float m = -3.4e38f;
    for (int b = ty; b < 256; b += 16) m = fmaxf(m, pmax[b * 16 + tx]);
    red[ty][tx] = m;
    __syncthreads();
    if (ty == 0) {
        float mm = red[0][tx];
#pragma unroll
        for (int i = 1; i < 16; ++i) mm = fmaxf(mm, red[i][tx]);
        gsh[tx] = mm;
    }
    __syncthreads();
    float g = gsh[tx];
    float s = 0.f;
    for (int b = ty; b < 256; b += 16)
        s += psum[b * 16 + tx] * expf(pmax[b * 16 + tx] - g);
    red[ty][tx] = s;
    __syncthreads();
    if (ty == 0) {
        float ss = red[0][tx];
#pragma unroll
        for (int i = 1; i < 16; ++i) ss += red[i][tx];
        g16[tx] = g;
        inv16[tx] = 1.0f / ss;
    }
}

__global__ void k_sm5(float* __restrict__ z, const float* __restrict__ g16,
                      const float* __restrict__ inv16, int total) {
    int i = blockIdx.x * 256 + threadIdx.x;
    if (i < total) {
        int c = i & 15;
        z[i] = expf(z[i] - g16[c]) * inv16[c];
    }
}

// ---------------------------------------------------------------------------
extern "C" void kernel_launch(void* const* d_in, const int* in_sizes, int n_in,
                              void* d_out, int out_size, void* d_ws, size_t ws_size,
                              hipStream_t stream) {
    const float* x  = (const float*)d_in[0];
    const int*   ei = (const int*)d_in[1];
    const float* W1 = (const float*)d_in[2];
    const float* b1 = (const float*)d_in[3];
    const float* Wi = (const float*)d_in[4];
    const float* bi = (const float*)d_in[5];
    const float* W2 = (const float*)d_in[6];
    const float* b2 = (const float*)d_in[7];
    float* out = (float*)d_out;

    int Nn = in_sizes[0] / NFEAT;   // 100000
    int E  = in_sizes[1] / 2;       // 1600000
    int nb = (Nn + 255) >> 8;       // 391 coarse buckets
    const int* esrc = ei;
    const int* edst = ei + E;

    char* p = (char*)d_ws;
    auto carve = [&](size_t bytes) -> char* {
        char* r = p;
        p += (bytes + 255) / 256 * 256;
        return r;
    };
    uint*  bufA    = (uint*) carve((size_t)Nn * 128 * 4);   // bf16 features
    uint*  bufB    = (uint*) carve((size_t)Nn * 128 * 4);
    int*   rowptr  = (int*)  carve((size_t)(Nn + 1) * 4);
    float* dis     = (float*)carve((size_t)Nn * 4);
    int*   csr_col = (int*)  carve((size_t)E * 4);
    float* csr_val = (float*)carve((size_t)E * 4);
    uint2* ebuf    = (uint2*)carve((size_t)E * 8);
    int*   bhist   = (int*)  carve(512 * 4);
    int*   boff    = (int*)  carve(512 * 4);
    int*   gcur    = (int*)  carve(512 * 4);
    float* y16     = (float*)carve((size_t)Nn * NCLS * 4);
    float* WA      = (float*)carve(256 * 256 * 4);   // T = W1 Wi
    float* WB      = (float*)carve(256 * 256 * 4);   // S = Wi Wi
    uint*  Wp      = (uint*) carve(32768 * 4);
    float* c1      = (float*)carve(256 * 4);
    float* c2      = (float*)carve(256 * 4);
    float* c3      = (float*)carve(256 * 4);
    float* pmax    = (float*)carve(256 * 16 * 4);
    float* psum    = (float*)carve(256 * 16 * 4);
    float* g16     = (float*)carve(16 * 4);
    float* inv16   = (float*)carve(16 * 4);

    hipMemsetAsync(bhist, 0, 512 * 4, stream);

    int gE = (E + 255) / 256;
    int nch = (E + 4095) / 4096;

    // graph build (bucketed counting sort)
    k_ccount<<<1024, 256, 0, stream>>>(edst, bhist, E, nb);
    k_cscan<<<1, 256, 0, stream>>>(bhist, boff, gcur, rowptr, nb, Nn);
    k_cfill<<<nch, 256, 0, stream>>>(esrc, edst, gcur, ebuf, E, nb);
    k_rowbuild<<<nb, 256, 0, stream>>>(ebuf, boff, rowptr, dis, csr_col, Nn, nb);
    k_val<<<gE, 256, 0, stream>>>(csr_col, dis, csr_val, E);

    // weight chain: {T, S} ; Wp = pack(T S) ; bias vectors c1=b1Wi^3, c2=biWi^2, c3=biWi
    k_mmTS<<<512, 256, 0, stream>>>(W1, Wi, WA, WB);
    k_mm256pack<<<128, 256, 0, stream>>>(WA, WB, Wp);
    k_vchain<<<1, 256, 0, stream>>>(b1, bi, Wi, c1, c2, c3);

    // y0 = x @ Wc  (fp32 in, bf16 out, MFMA; A read once)
    gemm_mfma<<<(Nn + 31) / 32, 256, 0, stream>>>(x, Wp, (ushort*)bufB, Nn);

    // y_{k+1} = A_hat y_k + 1 (x) c_k   (bias folded per pass; no scalar chain)
    int gA = (Nn + 3) / 4;
    k_aggb<<<gA, 256, 0, stream>>>(bufB, rowptr, csr_col, csr_val, dis, c1, bufA, Nn);
    k_aggb<<<gA, 256, 0, stream>>>(bufA, rowptr, csr_col, csr_val, dis, c2, bufB, Nn);
    k_aggb<<<gA, 256, 0, stream>>>(bufB, rowptr, csr_col, csr_val, dis, c3, bufA, Nn);
    k_aggb<<<gA, 256, 0, stream>>>(bufA, rowptr, csr_col, csr_val, dis, bi, bufB, Nn);

    // final: z = A(relu(h4) W2) + b2 ; softmax over nodes
    int g16b = (Nn + 15) / 16;
    k_gemm16b<<<g16b, 256, 0, stream>>>(bufB, W2, y16, Nn);
    k_agg16<<<g16b, 256, 0, stream>>>(y16, rowptr, csr_col, csr_val, dis, b2, out, Nn);

    k_sm1<<<256, 256, 0, stream>>>(out, pmax, psum, Nn);
    k_sm2<<<1, 256, 0, stream>>>(pmax, psum, g16, inv16);
    k_sm5<<<(Nn * NCLS + 255) / 256, 256, 0, stream>>>(out, g16, inv16, Nn * NCLS);
}